// Round 3
// baseline (8976.038 us; speedup 1.0000x reference)
//
#include <hip/hip_runtime.h>

// Shapes (fixed): B=4 S=1024 D=1024 H=16 HD=64 C=64 NC=16 DFF=256
// All external I/O and inter-kernel buffers are float32 (per reference dtypes).
typedef short v8s __attribute__((ext_vector_type(8)));
typedef short v4s __attribute__((ext_vector_type(4)));
typedef float v4f __attribute__((ext_vector_type(4)));

__device__ __forceinline__ unsigned short fbf(float f){
  unsigned u = __float_as_uint(f);
  u += 0x7fffu + ((u>>16)&1u);
  return (unsigned short)(u>>16);
}
__device__ __forceinline__ float wsum(float v){
  #pragma unroll
  for (int off=32; off>0; off>>=1) v += __shfl_xor(v, off, 64);
  return v;
}
__device__ __forceinline__ float wmaxf(float v){
  #pragma unroll
  for (int off=32; off>0; off>>=1) v = fmaxf(v, __shfl_xor(v, off, 64));
  return v;
}
__device__ __forceinline__ float clampv(float x){ return fminf(fmaxf(x, -1e8f), 1e8f); }
__device__ __forceinline__ float tanh_f(float x){
  x = fminf(fmaxf(x, -15.f), 15.f);
  float e = __expf(2.f*x);
  return (e-1.f)/(e+1.f);
}
__device__ __forceinline__ float gelu_f(float x){
  float t = tanh_f(0.79788456f*(x + 0.044715f*x*x*x));
  return 0.5f*x*(1.f+t);
}
__device__ __forceinline__ float gelu_bwd_f(float x){
  float t = tanh_f(0.79788456f*(x + 0.044715f*x*x*x));
  return 0.5f*x*(1.f-t*t)*(0.79788456f + 0.1070322243f*x*x) + 0.5f*(1.f+t);
}

// ---------------- LayerNorm over D=1024, one block per row ----------------
__global__ __launch_bounds__(256) void ln_kernel(
    const float* __restrict__ X, const float* __restrict__ g,
    const float* __restrict__ bta, float* __restrict__ out)
{
  __shared__ float red[4];
  int row = blockIdx.x, t = threadIdx.x;
  const float* xr = X + (size_t)row*1024;
  float v[4];
  #pragma unroll
  for (int i=0;i<4;i++) v[i] = xr[t + i*256];
  float s = v[0]+v[1]+v[2]+v[3];
  s = wsum(s);
  if ((t&63)==0) red[t>>6]=s;
  __syncthreads();
  float mu = (red[0]+red[1]+red[2]+red[3])*(1.f/1024.f);
  float q=0.f;
  #pragma unroll
  for (int i=0;i<4;i++){ float dd=v[i]-mu; q+=dd*dd; }
  q = wsum(q);
  __syncthreads();
  if ((t&63)==0) red[t>>6]=q;
  __syncthreads();
  float var = (red[0]+red[1]+red[2]+red[3])*(1.f/1024.f);
  float rs = rsqrtf(var+1e-6f);
  #pragma unroll
  for (int i=0;i<4;i++){
    int c = t+i*256;
    out[(size_t)row*1024+c] = (v[i]-mu)*rs*g[c] + bta[c];
  }
}

// ---- MFMA GEMM: out[m,n] = gate(n)*(A[4096,1024]@Bw[1024,1024]^T + bias(n)) + res[m,n]
// f32 in/out; bf16 MFMA internally (convert during LDS staging), f32 accumulate.
__global__ __launch_bounds__(256) void gemm_kernel(
    const float* __restrict__ A, const float* __restrict__ Bw,
    const float* __restrict__ bias, const float* __restrict__ res,
    const float* __restrict__ gate, float* __restrict__ out)
{
  __shared__ __attribute__((aligned(16))) short a_lds[128*40];
  __shared__ __attribute__((aligned(16))) short b_lds[128*40];
  int t=threadIdx.x, w=t>>6, lane=t&63;
  int gm = blockIdx.y*128, gn = blockIdx.x*128;
  int wm = (w>>1)*64, wn = (w&1)*64;
  int lr = lane&15, lk = (lane>>4)*8;
  v4f acc[4][4];
  #pragma unroll
  for (int i=0;i<4;i++)
    #pragma unroll
    for (int j=0;j<4;j++){ v4f z = {0.f,0.f,0.f,0.f}; acc[i][j]=z; }
  for (int kk=0; kk<1024; kk+=32){
    __syncthreads();
    #pragma unroll
    for (int pass=0;pass<4;pass++){
      int slot=t+pass*256, row=slot>>3, c4=(slot&7)*4;
      float4 av = *(const float4*)&A[(size_t)(gm+row)*1024 + kk + c4];
      float4 bv = *(const float4*)&Bw[(size_t)(gn+row)*1024 + kk + c4];
      v4s at, bt;
      at[0]=(short)fbf(av.x); at[1]=(short)fbf(av.y); at[2]=(short)fbf(av.z); at[3]=(short)fbf(av.w);
      bt[0]=(short)fbf(bv.x); bt[1]=(short)fbf(bv.y); bt[2]=(short)fbf(bv.z); bt[3]=(short)fbf(bv.w);
      *(v4s*)&a_lds[row*40+c4] = at;
      *(v4s*)&b_lds[row*40+c4] = bt;
    }
    __syncthreads();
    v8s af[4], bfr[4];
    #pragma unroll
    for (int i=0;i<4;i++) af[i] = *(const v8s*)&a_lds[(wm+i*16+lr)*40+lk];
    #pragma unroll
    for (int j=0;j<4;j++) bfr[j] = *(const v8s*)&b_lds[(wn+j*16+lr)*40+lk];
    #pragma unroll
    for (int i=0;i<4;i++)
      #pragma unroll
      for (int j=0;j<4;j++)
        acc[i][j] = __builtin_amdgcn_mfma_f32_16x16x32_bf16(af[i], bfr[j], acc[i][j], 0,0,0);
  }
  int quad = lane>>4;
  #pragma unroll
  for (int j=0;j<4;j++){
    int gc = gn + wn + j*16 + lr;
    float bval = bias ? bias[gc] : 0.f;
    float gval = gate ? tanh_f(gate[gc]) : 1.f;
    #pragma unroll
    for (int i=0;i<4;i++){
      #pragma unroll
      for (int r=0;r<4;r++){
        int grow = gm + wm + i*16 + quad*4 + r;
        float v = (acc[i][j][r] + bval)*gval;
        if (res) v += res[(size_t)grow*1024 + gc];
        out[(size_t)grow*1024 + gc] = v;
      }
    }
  }
}

// ---------------- Flash attention, block = (b,h,q-tile of 64) ----------------
__global__ __launch_bounds__(256) void attn_kernel(
    const float* __restrict__ Q, const float* __restrict__ K,
    const float* __restrict__ V, float* __restrict__ O)
{
  __shared__ __attribute__((aligned(16))) float q_lds[64*68];
  __shared__ __attribute__((aligned(16))) float k_lds[64*68];
  __shared__ __attribute__((aligned(16))) float v_lds[64*68];
  __shared__ __attribute__((aligned(16))) float p_lds[4][16][64];
  int t=threadIdx.x, w=t>>6, lane=t&63;
  int qt = blockIdx.x & 15, bh = blockIdx.x >> 4;
  int b = bh >> 4, h = bh & 15;
  const size_t base = ((size_t)b*1024)*1024 + (size_t)h*64;
  #pragma unroll
  for (int pass=0;pass<4;pass++){
    int slot=t+pass*256, row=slot>>4, c4=(slot&15)*4;
    *(float4*)&q_lds[row*68+c4] = *(const float4*)&Q[base + (size_t)(qt*64+row)*1024 + c4];
  }
  float mi[16], li[16], o[16], al[16];
  #pragma unroll
  for (int i=0;i<16;i++){ mi[i]=-1e30f; li[i]=0.f; o[i]=0.f; al[i]=0.f; }
  for (int kt=0; kt<=qt; kt++){
    __syncthreads();
    #pragma unroll
    for (int pass=0;pass<4;pass++){
      int slot=t+pass*256, row=slot>>4, c4=(slot&15)*4;
      *(float4*)&k_lds[row*68+c4] = *(const float4*)&K[base + (size_t)(kt*64+row)*1024 + c4];
      *(float4*)&v_lds[row*68+c4] = *(const float4*)&V[base + (size_t)(kt*64+row)*1024 + c4];
    }
    __syncthreads();
    #pragma unroll 1
    for (int i=0;i<16;i++){
      int r=w*16+i, sq=qt*64+r;
      float s=0.f;
      #pragma unroll
      for (int d4=0;d4<16;d4++){
        const float4 q4 = *(const float4*)&q_lds[r*68+d4*4];
        const float4 k4 = *(const float4*)&k_lds[lane*68+d4*4];
        s += q4.x*k4.x + q4.y*k4.y + q4.z*k4.z + q4.w*k4.w;
      }
      s *= 0.125f;
      bool ok = (kt*64+lane) <= sq;
      float sm = ok ? s : -1e30f;
      float mx = wmaxf(sm);
      float mnew = fmaxf(mi[i], mx);
      float aexp = __expf(mi[i]-mnew);
      float p = ok ? __expf(s-mnew) : 0.f;
      float ps = wsum(p);
      li[i] = li[i]*aexp + ps;
      mi[i] = mnew;
      al[i] = aexp;
      p_lds[w][i][lane] = p;
    }
    __syncthreads();
    #pragma unroll 1
    for (int i=0;i<16;i++){
      float acc = o[i]*al[i];
      #pragma unroll
      for (int j4=0;j4<16;j4++){
        const float4 p4 = *(const float4*)&p_lds[w][i][j4*4];
        acc += p4.x*v_lds[(j4*4+0)*68+lane]
             + p4.y*v_lds[(j4*4+1)*68+lane]
             + p4.z*v_lds[(j4*4+2)*68+lane]
             + p4.w*v_lds[(j4*4+3)*68+lane];
      }
      o[i]=acc;
    }
  }
  #pragma unroll
  for (int i=0;i<16;i++){
    int r=w*16+i;
    O[base + (size_t)(qt*64+r)*1024 + lane] = o[i]/li[i];
  }
}

// ------- XQ/XK normalize + XV fuse; write TTT layout [B,H,S,HD]. wave = (b,s,h) -------
__global__ __launch_bounds__(256) void xqkv_kernel(
    const float* __restrict__ XQ, const float* __restrict__ XK,
    const float* __restrict__ XV, const float* __restrict__ nw,
    const float* __restrict__ nb,
    float* __restrict__ xqt, float* __restrict__ xkt, float* __restrict__ xvt)
{
  int gw = (int)((blockIdx.x*256 + threadIdx.x)>>6);
  int lane = threadIdx.x & 63;
  int h = gw & 15, s = (gw>>4)&1023, b = gw>>14;
  size_t src = ((size_t)(b*1024+s))*1024 + h*64 + lane;
  float xq = XQ[src], xk = XK[src], xv = XV[src];
  float nq = sqrtf(wsum(xq*xq));
  float nk = sqrtf(wsum(xk*xk));
  float xqn = xq / fmaxf(nq, 1e-12f);
  float xkn = xk / fmaxf(nk, 1e-12f);
  float mu = wsum(xv)*(1.f/64.f);
  float xm = xv-mu;
  float var = wsum(xm*xm)*(1.f/64.f);
  float xvh = xm*rsqrtf(var+1e-6f);
  float xvn = nw[h*64+lane]*xvh + nb[h*64+lane] + xkn;
  size_t dst = ((size_t)(b*16+h)*1024 + s)*64 + lane;
  xqt[dst]=xqn; xkt[dst]=xkn; xvt[dst]=xvn;
}

// ------- eta[b,h,s] = sigmoid(x[b,s,:]·lr_w[h,:] + lr_b[h]) / 64. wave = (b,s) -------
__global__ __launch_bounds__(256) void eta_kernel(
    const float* __restrict__ Xb, const float* __restrict__ lrw,
    const float* __restrict__ lrb, float* __restrict__ eta)
{
  int gw = (int)((blockIdx.x*256 + threadIdx.x)>>6);
  int lane = threadIdx.x & 63;
  int s = gw & 1023, b = gw >> 10;
  const float* xrow = Xb + ((size_t)(b*1024+s))*1024;
  float xr[16];
  #pragma unroll
  for (int i=0;i<16;i++) xr[i] = xrow[i*64+lane];
  #pragma unroll 1
  for (int h=0;h<16;h++){
    const float* wr = lrw + h*1024;
    float acc=0.f;
    #pragma unroll
    for (int i=0;i<16;i++) acc += xr[i]*wr[i*64+lane];
    acc = wsum(acc);
    if (lane==h){
      float vv = acc + lrb[h];
      float sg = 1.f/(1.f+__expf(-vv));
      eta[((size_t)(b*16+h))*1024 + s] = sg*(1.f/64.f);
    }
  }
}

// ---------------- TTT scan: one block per (b,h), 16 sequential chunks ----------------
#define SCRF 69632
__global__ __launch_bounds__(1024) void scan_kernel(
    const float* __restrict__ xqt, const float* __restrict__ xkt,
    const float* __restrict__ xvt, const float* __restrict__ eta,
    const float* __restrict__ W1in, const float* __restrict__ b1in,
    const float* __restrict__ W2in, const float* __restrict__ b2in,
    const float* __restrict__ nw, const float* __restrict__ nb,
    float* __restrict__ W1g, float* __restrict__ W2g,
    float* __restrict__ b1g, float* __restrict__ b2g,
    float* __restrict__ scr, float* __restrict__ tout)
{
  __shared__ __attribute__((aligned(16))) float xq_s[64*68];
  __shared__ __attribute__((aligned(16))) float xk_s[64*68];
  __shared__ __attribute__((aligned(16))) float A_s[64*68];
  __shared__ float eta_s[64];
  int t = threadIdx.x, w = t>>6, lane = t&63;
  int bh = blockIdx.x, b = bh>>4, h = bh&15;
  float* W1 = W1g + (size_t)bh*16384;   // [k<64][n<256]
  float* W2 = W2g + (size_t)bh*16384;   // [k<256][d<64]
  float* b1 = b1g + bh*256;
  float* b2 = b2g + bh*64;
  float* X2  = scr + (size_t)bh*SCRF;   // [64][256]
  float* G1  = X2  + 16384;
  float* gZ1 = G1  + 16384;
  float* X2b = gZ1 + 16384;
  float* gZ2 = X2b + 16384;             // [64][64]
  const float* xq_g = xqt + (size_t)bh*65536;
  const float* xk_g = xkt + (size_t)bh*65536;
  const float* xv_g = xvt + (size_t)bh*65536;
  const float* eta_g = eta + (size_t)bh*1024;
  for (int i=t; i<16384; i+=1024){
    W1[i] = W1in[h*16384+i];
    W2[i] = W2in[h*16384+i];
  }
  if (t<256) b1[t] = b1in[h*256+t];
  if (t<64)  b2[t] = b2in[h*64+t];
  float gwd = nw[h*64+lane];
  float gbd = nb[h*64+lane];

  for (int n=0;n<16;n++){
    __syncthreads();
    for (int i=t;i<4096;i+=1024){
      int r=i>>6, d=i&63;
      xq_s[r*68+d] = xq_g[n*4096+i];
      xk_s[r*68+d] = xk_g[n*4096+i];
    }
    if (t<64) eta_s[t] = eta_g[n*64+t];
    __syncthreads();
    // Phase A: Z1 = xk@W1 + b1 ; X2 = gelu(Z1), G1 = gelu'(Z1)
    {
      int nf=t&255, mb=t>>8;
      float acc[16];
      float bb = b1[nf];
      #pragma unroll
      for (int m=0;m<16;m++) acc[m]=bb;
      for (int k4=0;k4<16;k4++){
        float w0=W1[(k4*4+0)*256+nf], w1=W1[(k4*4+1)*256+nf],
              w2=W1[(k4*4+2)*256+nf], w3=W1[(k4*4+3)*256+nf];
        #pragma unroll
        for (int m=0;m<16;m++){
          const float4 x4 = *(const float4*)&xk_s[(mb*16+m)*68 + k4*4];
          acc[m] += x4.x*w0 + x4.y*w1 + x4.z*w2 + x4.w*w3;
        }
      }
      #pragma unroll
      for (int m=0;m<16;m++){
        int row = mb*16+m;
        float z = clampv(acc[m]);
        X2[row*256+nf] = clampv(gelu_f(z));
        G1[row*256+nf] = clampv(gelu_bwd_f(z));
      }
    }
    __syncthreads();
    // Phase B: Z2 = X2@W2 + b2 ; gZ2 = ln_l2_bwd(Z2, xv-xk)
    {
      float z[4];
      #pragma unroll
      for (int i=0;i<4;i++) z[i]=b2[lane];
      for (int k=0;k<256;k++){
        float wv = W2[k*64+lane];
        #pragma unroll
        for (int i=0;i<4;i++) z[i] += X2[(w*4+i)*256+k]*wv;
      }
      #pragma unroll
      for (int i=0;i<4;i++){
        int r=w*4+i;
        float zz=clampv(z[i]);
        float mu = wsum(zz)*(1.f/64.f);
        float xm = zz-mu;
        float var = wsum(xm*xm)*(1.f/64.f);
        float stdv = sqrtf(var+1e-6f);
        float xh = xm/stdv;
        float tgt = xv_g[n*4096 + r*64 + lane] - xk_s[r*68+lane];
        float gh = (gwd*xh + gbd - tgt)*gwd;
        float s1 = wsum(gh), s2 = wsum(gh*xh);
        gZ2[r*64+lane] = clampv((64.f*gh - s1 - xh*s2)/(64.f*stdv));
      }
    }
    __syncthreads();
    // Phase C: gZ1 = (gZ2 @ W2^T) * G1
    {
      int nf=t&255, mb=t>>8;
      float acc[16];
      #pragma unroll
      for (int m=0;m<16;m++) acc[m]=0.f;
      for (int d=0; d<64; d++){
        float wv = W2[nf*64+d];
        #pragma unroll
        for (int m=0;m<16;m++) acc[m] += gZ2[(mb*16+m)*64+d]*wv;
      }
      #pragma unroll
      for (int m=0;m<16;m++){
        int row=mb*16+m;
        gZ1[row*256+nf] = clampv(acc[m]*G1[row*256+nf]);
      }
    }
    __syncthreads();
    // Phase D: A_s[i][j] = (j<=i) ? eta_j*(xq_i·xk_j + 1) : 0
    {
      #pragma unroll
      for (int ii=0;ii<4;ii++){
        int i = w*4+ii;
        float a=0.f;
        #pragma unroll
        for (int d4=0;d4<16;d4++){
          const float4 q4 = *(const float4*)&xq_s[i*68 + d4*4];
          const float4 k4 = *(const float4*)&xk_s[lane*68 + d4*4];
          a += q4.x*k4.x + q4.y*k4.y + q4.z*k4.z + q4.w*k4.w;
        }
        A_s[i*68+lane] = (lane<=i) ? eta_s[lane]*(a+1.f) : 0.f;
      }
    }
    __syncthreads();
    // Phase E: Z1b = xq@W1 + b1 - A_s@gZ1 ; X2b = gelu(Z1b)
    {
      int nf=t&255, mb=t>>8;
      float acc[16];
      float bb=b1[nf];
      #pragma unroll
      for (int m=0;m<16;m++) acc[m]=bb;
      for (int k4=0;k4<16;k4++){
        float w0=W1[(k4*4+0)*256+nf], w1=W1[(k4*4+1)*256+nf],
              w2=W1[(k4*4+2)*256+nf], w3=W1[(k4*4+3)*256+nf];
        #pragma unroll
        for (int m=0;m<16;m++){
          const float4 x4 = *(const float4*)&xq_s[(mb*16+m)*68 + k4*4];
          acc[m] += x4.x*w0 + x4.y*w1 + x4.z*w2 + x4.w*w3;
        }
      }
      for (int j4=0;j4<16;j4++){
        float g0=gZ1[(j4*4+0)*256+nf], g1=gZ1[(j4*4+1)*256+nf],
              g2=gZ1[(j4*4+2)*256+nf], g3=gZ1[(j4*4+3)*256+nf];
        #pragma unroll
        for (int m=0;m<16;m++){
          const float4 a4 = *(const float4*)&A_s[(mb*16+m)*68 + j4*4];
          acc[m] -= a4.x*g0 + a4.y*g1 + a4.z*g2 + a4.w*g3;
        }
      }
      #pragma unroll
      for (int m=0;m<16;m++){
        int row=mb*16+m;
        X2b[row*256+nf] = clampv(gelu_f(clampv(acc[m])));
      }
    }
    __syncthreads();
    // Phase F: A_s[i][j] = (j<=i) ? eta_j*(X2b_i·X2_j + 1) : 0
    {
      #pragma unroll
      for (int ii=0;ii<4;ii++){
        int i=w*4+ii;
        float a=0.f;
        for (int k4=0;k4<64;k4++){
          const float4 xb4 = *(const float4*)&X2b[i*256 + k4*4];
          const float4 x24 = *(const float4*)&X2[lane*256 + k4*4];
          a += xb4.x*x24.x + xb4.y*x24.y + xb4.z*x24.z + xb4.w*x24.w;
        }
        A_s[i*68+lane] = (lane<=i) ? eta_s[lane]*(a+1.f) : 0.f;
      }
    }
    __syncthreads();
    // Phase G: Z2b = X2b@W2 + b2 - A_s@gZ2 ; out = xq + LN(Z2b)*gw + gb
    {
      float z[4];
      #pragma unroll
      for (int i=0;i<4;i++) z[i]=b2[lane];
      for (int k=0;k<256;k++){
        float wv=W2[k*64+lane];
        #pragma unroll
        for (int i=0;i<4;i++) z[i]+=X2b[(w*4+i)*256+k]*wv;
      }
      for (int j=0;j<64;j++){
        float gz=gZ2[j*64+lane];
        #pragma unroll
        for (int i=0;i<4;i++) z[i]-=A_s[(w*4+i)*68+j]*gz;
      }
      #pragma unroll
      for (int i=0;i<4;i++){
        int r=w*4+i;
        float zz=clampv(z[i]);
        float mu=wsum(zz)*(1.f/64.f);
        float xm=zz-mu;
        float var=wsum(xm*xm)*(1.f/64.f);
        float xh=xm*rsqrtf(var+1e-6f);
        float outv=xq_s[r*68+lane] + xh*gwd + gbd;
        tout[((size_t)(b*1024 + n*64 + r))*1024 + h*64 + lane] = outv;
      }
    }
    __syncthreads();
    // Phase G2: A_s[j][d] = eta_j * gZ2[j][d]
    for (int i=t;i<4096;i+=1024){
      int j=i>>6, d=i&63;
      A_s[j*68+d] = eta_s[j]*gZ2[i];
    }
    __syncthreads();
    // Phase H1: W1 -= xk^T diag(eta) gZ1 ; b1 -= Sum_j eta_j gZ1[j]
    {
      int nf=t&255, kb=t>>8;
      float acc[16];
      #pragma unroll
      for (int k=0;k<16;k++) acc[k]=0.f;
      float bacc=0.f;
      for (int j=0;j<64;j++){
        float g = eta_s[j]*gZ1[j*256+nf];
        bacc += g;
        #pragma unroll
        for (int k4=0;k4<4;k4++){
          const float4 x4 = *(const float4*)&xk_s[j*68 + kb*16 + k4*4];
          acc[k4*4+0]+=x4.x*g; acc[k4*4+1]+=x4.y*g; acc[k4*4+2]+=x4.z*g; acc[k4*4+3]+=x4.w*g;
        }
      }
      #pragma unroll
      for (int k=0;k<16;k++){
        int idx=(kb*16+k)*256+nf;
        W1[idx] -= acc[k];
      }
      if (kb==0) b1[nf] -= bacc;
    }
    // Phase H2: W2 -= X2^T diag(eta) gZ2 ; b2 -= Sum_j eta_j gZ2[j]
    {
      int d=t&63, kb=t>>6;
      float acc[16];
      #pragma unroll
      for (int k=0;k<16;k++) acc[k]=0.f;
      float bacc=0.f;
      for (int j=0;j<64;j++){
        float a = A_s[j*68+d];
        bacc += a;
        #pragma unroll
        for (int k4=0;k4<4;k4++){
          const float4 x4 = *(const float4*)&X2[j*256 + kb*16 + k4*4];
          acc[k4*4+0]+=x4.x*a; acc[k4*4+1]+=x4.y*a; acc[k4*4+2]+=x4.z*a; acc[k4*4+3]+=x4.w*a;
        }
      }
      #pragma unroll
      for (int k=0;k<16;k++){
        int idx=(kb*16+k)*64+d;
        W2[idx] -= acc[k];
      }
      if (kb==0) b2[d] -= bacc;
    }
  }
}

extern "C" void kernel_launch(void* const* d_in, const int* in_sizes, int n_in,
                              void* d_out, int out_size, void* d_ws, size_t ws_size,
                              hipStream_t stream)
{
  const float* x_in   = (const float*)d_in[0];
  const float* ln1w   = (const float*)d_in[1];
  const float* ln1b   = (const float*)d_in[2];
  const float* awq    = (const float*)d_in[3];
  const float* awk    = (const float*)d_in[4];
  const float* awv    = (const float*)d_in[5];
  const float* awo    = (const float*)d_in[6];
  const float* wqw    = (const float*)d_in[7];
  const float* wqb    = (const float*)d_in[8];
  const float* wkw    = (const float*)d_in[9];
  const float* wkb    = (const float*)d_in[10];
  const float* wvw    = (const float*)d_in[11];
  const float* wvb    = (const float*)d_in[12];
  const float* wow    = (const float*)d_in[13];
  const float* wob    = (const float*)d_in[14];
  const float* W1in   = (const float*)d_in[15];
  const float* b1in   = (const float*)d_in[16];
  const float* W2in   = (const float*)d_in[17];
  const float* b2in   = (const float*)d_in[18];
  const float* tnw    = (const float*)d_in[19];
  const float* tnb    = (const float*)d_in[20];
  const float* lrw    = (const float*)d_in[21];
  const float* lrb    = (const float*)d_in[22];
  const float* pnw    = (const float*)d_in[23];
  const float* pnb    = (const float*)d_in[24];
  const float* galpha = (const float*)d_in[25];
  float* outp = (float*)d_out;
  char* ws = (char*)d_ws;
  const size_t MB = (size_t)1<<20;
  // f32 layout, 16MB per [4096,1024] buffer. High-water ~145.5 MB.
  //  @0:   bq   (scan: scr 17.8MB spans @0-18)
  //  @16:  bk
  //  @32:  bv   (scan: W1g @36, W2g @40, each 4MB — bv dead after xqkv)
  //  @48:  bhh  (post-LN reuses after scan)
  //  @64:  bo   (scan tout reuses — bo dead after wo-gemm)
  //  @80:  bxb  (residual, live to end)
  //  @96:  xqt  @112: xkt  @128: xvt
  //  @144: eta(256KB) @+512KB: b1g(64KB) @+768KB: b2g(16KB)
  float* bq  = (float*)(ws + 0*MB);
  float* bk  = (float*)(ws + 16*MB);
  float* bv  = (float*)(ws + 32*MB);
  float* bhh = (float*)(ws + 48*MB);
  float* bo  = (float*)(ws + 64*MB);
  float* bxb = (float*)(ws + 80*MB);
  float* xqt = (float*)(ws + 96*MB);
  float* xkt = (float*)(ws + 112*MB);
  float* xvt = (float*)(ws + 128*MB);
  float* eta  = (float*)(ws + 144*MB);
  float* b1g  = (float*)(ws + 144*MB + 512*1024);
  float* b2g  = (float*)(ws + 144*MB + 768*1024);
  float* scr  = (float*)(ws + 0*MB);    // overlays bq/bk (dead after xqkv)
  float* W1g  = (float*)(ws + 36*MB);   // overlays bv (dead after xqkv)
  float* W2g  = (float*)(ws + 40*MB);
  float* tout = bo;                     // overlays bo (dead after wo-gemm)
  float* bhh2 = bhh;                    // post-LN out (bhh dead after scan)

  dim3 gg(8,32);
  ln_kernel<<<4096,256,0,stream>>>(x_in, ln1w, ln1b, bhh);
  gemm_kernel<<<gg,256,0,stream>>>(bhh, awq, nullptr, nullptr, nullptr, bq);
  gemm_kernel<<<gg,256,0,stream>>>(bhh, awk, nullptr, nullptr, nullptr, bk);
  gemm_kernel<<<gg,256,0,stream>>>(bhh, awv, nullptr, nullptr, nullptr, bv);
  attn_kernel<<<1024,256,0,stream>>>(bq,bk,bv,bo);
  gemm_kernel<<<gg,256,0,stream>>>(bo, awo, nullptr, x_in, nullptr, bxb);
  gemm_kernel<<<gg,256,0,stream>>>(bxb, wqw, wqb, nullptr, nullptr, bq);
  gemm_kernel<<<gg,256,0,stream>>>(bxb, wkw, wkb, nullptr, nullptr, bk);
  gemm_kernel<<<gg,256,0,stream>>>(bxb, wvw, wvb, nullptr, nullptr, bv);
  xqkv_kernel<<<16384,256,0,stream>>>(bq,bk,bv,tnw,tnb,xqt,xkt,xvt);
  eta_kernel<<<1024,256,0,stream>>>(bxb, lrw, lrb, eta);
  scan_kernel<<<64,1024,0,stream>>>(xqt,xkt,xvt,eta,W1in,b1in,W2in,b2in,tnw,tnb,
                                    W1g,W2g,b1g,b2g,scr,tout);
  ln_kernel<<<4096,256,0,stream>>>(tout, pnw, pnb, bhh2);
  gemm_kernel<<<gg,256,0,stream>>>(bhh2, wow, wob, bxb, galpha, outp);
}

// Round 4
// 5499.149 us; speedup vs baseline: 1.6323x; 1.6323x over previous
//
#include <hip/hip_runtime.h>

// Shapes (fixed): B=4 S=1024 D=1024 H=16 HD=64 C=64 NC=16 DFF=256
// All external I/O and inter-kernel buffers are float32 (per reference dtypes).
typedef short v8s __attribute__((ext_vector_type(8)));
typedef short v4s __attribute__((ext_vector_type(4)));
typedef float v4f __attribute__((ext_vector_type(4)));

__device__ __forceinline__ float bfu(unsigned short u){ return __uint_as_float(((unsigned)u)<<16); }
__device__ __forceinline__ unsigned short fbf(float f){
  unsigned u = __float_as_uint(f);
  u += 0x7fffu + ((u>>16)&1u);
  return (unsigned short)(u>>16);
}
__device__ __forceinline__ float wsum(float v){
  #pragma unroll
  for (int off=32; off>0; off>>=1) v += __shfl_xor(v, off, 64);
  return v;
}
__device__ __forceinline__ float wmaxf(float v){
  #pragma unroll
  for (int off=32; off>0; off>>=1) v = fmaxf(v, __shfl_xor(v, off, 64));
  return v;
}
__device__ __forceinline__ float clampv(float x){ return fminf(fmaxf(x, -1e8f), 1e8f); }
__device__ __forceinline__ float tanh_f(float x){
  x = fminf(fmaxf(x, -15.f), 15.f);
  float e = __expf(2.f*x);
  return (e-1.f)/(e+1.f);
}
__device__ __forceinline__ float gelu_f(float x){
  float t = tanh_f(0.79788456f*(x + 0.044715f*x*x*x));
  return 0.5f*x*(1.f+t);
}
__device__ __forceinline__ float gelu_bwd_f(float x){
  float t = tanh_f(0.79788456f*(x + 0.044715f*x*x*x));
  return 0.5f*x*(1.f-t*t)*(0.79788456f + 0.1070322243f*x*x) + 0.5f*(1.f+t);
}

// ---------------- LayerNorm over D=1024, one block per row ----------------
__global__ __launch_bounds__(256) void ln_kernel(
    const float* __restrict__ X, const float* __restrict__ g,
    const float* __restrict__ bta, float* __restrict__ out)
{
  __shared__ float red[4];
  int row = blockIdx.x, t = threadIdx.x;
  const float* xr = X + (size_t)row*1024;
  float v[4];
  #pragma unroll
  for (int i=0;i<4;i++) v[i] = xr[t + i*256];
  float s = v[0]+v[1]+v[2]+v[3];
  s = wsum(s);
  if ((t&63)==0) red[t>>6]=s;
  __syncthreads();
  float mu = (red[0]+red[1]+red[2]+red[3])*(1.f/1024.f);
  float q=0.f;
  #pragma unroll
  for (int i=0;i<4;i++){ float dd=v[i]-mu; q+=dd*dd; }
  q = wsum(q);
  __syncthreads();
  if ((t&63)==0) red[t>>6]=q;
  __syncthreads();
  float var = (red[0]+red[1]+red[2]+red[3])*(1.f/1024.f);
  float rs = rsqrtf(var+1e-6f);
  #pragma unroll
  for (int i=0;i<4;i++){
    int c = t+i*256;
    out[(size_t)row*1024+c] = (v[i]-mu)*rs*g[c] + bta[c];
  }
}

// ---- MFMA GEMM: out[m,n] = gate(n)*(A[4096,1024]@Bw[1024,1024]^T + bias(n)) + res[m,n]
__global__ __launch_bounds__(256) void gemm_kernel(
    const float* __restrict__ A, const float* __restrict__ Bw,
    const float* __restrict__ bias, const float* __restrict__ res,
    const float* __restrict__ gate, float* __restrict__ out)
{
  __shared__ __attribute__((aligned(16))) short a_lds[128*40];
  __shared__ __attribute__((aligned(16))) short b_lds[128*40];
  int t=threadIdx.x, w=t>>6, lane=t&63;
  int gm = blockIdx.y*128, gn = blockIdx.x*128;
  int wm = (w>>1)*64, wn = (w&1)*64;
  int lr = lane&15, lk = (lane>>4)*8;
  v4f acc[4][4];
  #pragma unroll
  for (int i=0;i<4;i++)
    #pragma unroll
    for (int j=0;j<4;j++){ v4f z = {0.f,0.f,0.f,0.f}; acc[i][j]=z; }
  for (int kk=0; kk<1024; kk+=32){
    __syncthreads();
    #pragma unroll
    for (int pass=0;pass<4;pass++){
      int slot=t+pass*256, row=slot>>3, c4=(slot&7)*4;
      float4 av = *(const float4*)&A[(size_t)(gm+row)*1024 + kk + c4];
      float4 bv = *(const float4*)&Bw[(size_t)(gn+row)*1024 + kk + c4];
      v4s at, bt;
      at[0]=(short)fbf(av.x); at[1]=(short)fbf(av.y); at[2]=(short)fbf(av.z); at[3]=(short)fbf(av.w);
      bt[0]=(short)fbf(bv.x); bt[1]=(short)fbf(bv.y); bt[2]=(short)fbf(bv.z); bt[3]=(short)fbf(bv.w);
      *(v4s*)&a_lds[row*40+c4] = at;
      *(v4s*)&b_lds[row*40+c4] = bt;
    }
    __syncthreads();
    v8s af[4], bfr[4];
    #pragma unroll
    for (int i=0;i<4;i++) af[i] = *(const v8s*)&a_lds[(wm+i*16+lr)*40+lk];
    #pragma unroll
    for (int j=0;j<4;j++) bfr[j] = *(const v8s*)&b_lds[(wn+j*16+lr)*40+lk];
    #pragma unroll
    for (int i=0;i<4;i++)
      #pragma unroll
      for (int j=0;j<4;j++)
        acc[i][j] = __builtin_amdgcn_mfma_f32_16x16x32_bf16(af[i], bfr[j], acc[i][j], 0,0,0);
  }
  int quad = lane>>4;
  #pragma unroll
  for (int j=0;j<4;j++){
    int gc = gn + wn + j*16 + lr;
    float bval = bias ? bias[gc] : 0.f;
    float gval = gate ? tanh_f(gate[gc]) : 1.f;
    #pragma unroll
    for (int i=0;i<4;i++){
      #pragma unroll
      for (int r=0;r<4;r++){
        int grow = gm + wm + i*16 + quad*4 + r;
        float v = (acc[i][j][r] + bval)*gval;
        if (res) v += res[(size_t)grow*1024 + gc];
        out[(size_t)grow*1024 + gc] = v;
      }
    }
  }
}

// ---------------- Flash attention, block = (b,h,q-tile of 64) ----------------
__global__ __launch_bounds__(256) void attn_kernel(
    const float* __restrict__ Q, const float* __restrict__ K,
    const float* __restrict__ V, float* __restrict__ O)
{
  __shared__ __attribute__((aligned(16))) float q_lds[64*68];
  __shared__ __attribute__((aligned(16))) float k_lds[64*68];
  __shared__ __attribute__((aligned(16))) float v_lds[64*68];
  __shared__ __attribute__((aligned(16))) float p_lds[4][16][64];
  int t=threadIdx.x, w=t>>6, lane=t&63;
  int qt = blockIdx.x & 15, bh = blockIdx.x >> 4;
  int b = bh >> 4, h = bh & 15;
  const size_t base = ((size_t)b*1024)*1024 + (size_t)h*64;
  #pragma unroll
  for (int pass=0;pass<4;pass++){
    int slot=t+pass*256, row=slot>>4, c4=(slot&15)*4;
    *(float4*)&q_lds[row*68+c4] = *(const float4*)&Q[base + (size_t)(qt*64+row)*1024 + c4];
  }
  float mi[16], li[16], o[16], al[16];
  #pragma unroll
  for (int i=0;i<16;i++){ mi[i]=-1e30f; li[i]=0.f; o[i]=0.f; al[i]=0.f; }
  for (int kt=0; kt<=qt; kt++){
    __syncthreads();
    #pragma unroll
    for (int pass=0;pass<4;pass++){
      int slot=t+pass*256, row=slot>>4, c4=(slot&15)*4;
      *(float4*)&k_lds[row*68+c4] = *(const float4*)&K[base + (size_t)(kt*64+row)*1024 + c4];
      *(float4*)&v_lds[row*68+c4] = *(const float4*)&V[base + (size_t)(kt*64+row)*1024 + c4];
    }
    __syncthreads();
    #pragma unroll 1
    for (int i=0;i<16;i++){
      int r=w*16+i, sq=qt*64+r;
      float s=0.f;
      #pragma unroll
      for (int d4=0;d4<16;d4++){
        const float4 q4 = *(const float4*)&q_lds[r*68+d4*4];
        const float4 k4 = *(const float4*)&k_lds[lane*68+d4*4];
        s += q4.x*k4.x + q4.y*k4.y + q4.z*k4.z + q4.w*k4.w;
      }
      s *= 0.125f;
      bool ok = (kt*64+lane) <= sq;
      float sm = ok ? s : -1e30f;
      float mx = wmaxf(sm);
      float mnew = fmaxf(mi[i], mx);
      float aexp = __expf(mi[i]-mnew);
      float p = ok ? __expf(s-mnew) : 0.f;
      float ps = wsum(p);
      li[i] = li[i]*aexp + ps;
      mi[i] = mnew;
      al[i] = aexp;
      p_lds[w][i][lane] = p;
    }
    __syncthreads();
    #pragma unroll 1
    for (int i=0;i<16;i++){
      float acc = o[i]*al[i];
      #pragma unroll
      for (int j4=0;j4<16;j4++){
        const float4 p4 = *(const float4*)&p_lds[w][i][j4*4];
        acc += p4.x*v_lds[(j4*4+0)*68+lane]
             + p4.y*v_lds[(j4*4+1)*68+lane]
             + p4.z*v_lds[(j4*4+2)*68+lane]
             + p4.w*v_lds[(j4*4+3)*68+lane];
      }
      o[i]=acc;
    }
  }
  #pragma unroll
  for (int i=0;i<16;i++){
    int r=w*16+i;
    O[base + (size_t)(qt*64+r)*1024 + lane] = o[i]/li[i];
  }
}

// ------- XQ/XK normalize + XV fuse; write TTT layout [B,H,S,HD]. wave = (b,s,h) -------
__global__ __launch_bounds__(256) void xqkv_kernel(
    const float* __restrict__ XQ, const float* __restrict__ XK,
    const float* __restrict__ XV, const float* __restrict__ nw,
    const float* __restrict__ nb,
    float* __restrict__ xqt, float* __restrict__ xkt, float* __restrict__ xvt)
{
  int gw = (int)((blockIdx.x*256 + threadIdx.x)>>6);
  int lane = threadIdx.x & 63;
  int h = gw & 15, s = (gw>>4)&1023, b = gw>>14;
  size_t src = ((size_t)(b*1024+s))*1024 + h*64 + lane;
  float xq = XQ[src], xk = XK[src], xv = XV[src];
  float nq = sqrtf(wsum(xq*xq));
  float nk = sqrtf(wsum(xk*xk));
  float xqn = xq / fmaxf(nq, 1e-12f);
  float xkn = xk / fmaxf(nk, 1e-12f);
  float mu = wsum(xv)*(1.f/64.f);
  float xm = xv-mu;
  float var = wsum(xm*xm)*(1.f/64.f);
  float xvh = xm*rsqrtf(var+1e-6f);
  float xvn = nw[h*64+lane]*xvh + nb[h*64+lane] + xkn;
  size_t dst = ((size_t)(b*16+h)*1024 + s)*64 + lane;
  xqt[dst]=xqn; xkt[dst]=xkn; xvt[dst]=xvn;
}

// ------- eta[b,h,s] = sigmoid(x[b,s,:]·lr_w[h,:] + lr_b[h]) / 64. wave = (b,s) -------
__global__ __launch_bounds__(256) void eta_kernel(
    const float* __restrict__ Xb, const float* __restrict__ lrw,
    const float* __restrict__ lrb, float* __restrict__ eta)
{
  int gw = (int)((blockIdx.x*256 + threadIdx.x)>>6);
  int lane = threadIdx.x & 63;
  int s = gw & 1023, b = gw >> 10;
  const float* xrow = Xb + ((size_t)(b*1024+s))*1024;
  float xr[16];
  #pragma unroll
  for (int i=0;i<16;i++) xr[i] = xrow[i*64+lane];
  #pragma unroll 1
  for (int h=0;h<16;h++){
    const float* wr = lrw + h*1024;
    float acc=0.f;
    #pragma unroll
    for (int i=0;i<16;i++) acc += xr[i]*wr[i*64+lane];
    acc = wsum(acc);
    if (lane==h){
      float vv = acc + lrb[h];
      float sg = 1.f/(1.f+__expf(-vv));
      eta[((size_t)(b*16+h))*1024 + s] = sg*(1.f/64.f);
    }
  }
}

// ---------------- TTT scan (MFMA): one 512-thread block per (b,h) chain ----------------
// LDS-resident chunk state; W1/W2 f32 masters in global (L2-resident per block).
// MFMA 16x16x32 bf16 layouts (HW-verified): A/B frag: m|n=lane&15, k=quad*8+j;
// C/D frag: col=lane&15, row=quad*4+reg.
__global__ __launch_bounds__(512) void scan_kernel(
    const float* __restrict__ xqt, const float* __restrict__ xkt,
    const float* __restrict__ xvt, const float* __restrict__ eta,
    const float* __restrict__ W1in, const float* __restrict__ b1in,
    const float* __restrict__ W2in, const float* __restrict__ b2in,
    const float* __restrict__ nw, const float* __restrict__ nb,
    float* __restrict__ W1g, float* __restrict__ W2g,
    float* __restrict__ tout)
{
  // strides in ushorts: small 64-wide = 72, wide 256-wide = 264 (both keep b128 align, 2-way banks)
  __shared__ __attribute__((aligned(16))) unsigned short xq_s[64*72];
  __shared__ __attribute__((aligned(16))) unsigned short xk_s[64*72];
  __shared__ __attribute__((aligned(16))) unsigned short gZ2_s[64*72];
  __shared__ __attribute__((aligned(16))) unsigned short Am_s[64*72];   // NEGATED eta*(A+1), masked
  __shared__ __attribute__((aligned(16))) unsigned short X2_s[64*264];
  __shared__ __attribute__((aligned(16))) unsigned short GX_s[64*264];  // G1 (P1->P3) then X2b (P5->P7)
  __shared__ __attribute__((aligned(16))) unsigned short gZ1_s[64*264];
  __shared__ __attribute__((aligned(16))) float Zs[64*68];              // f32 LN scratch (P2, P7)
  __shared__ float eta_s[64];
  __shared__ float b1_s[256];
  __shared__ float b2_s[64];

  int t=threadIdx.x, w=t>>6, lane=t&63, q=lane>>4, l16=lane&15;
  int bh=blockIdx.x, b=bh>>4, h=bh&15;
  float* W1 = W1g + (size_t)bh*16384;   // [k<64][n<256]
  float* W2 = W2g + (size_t)bh*16384;   // [k<256][d<64]
  const float* xq_g = xqt + (size_t)bh*65536;
  const float* xk_g = xkt + (size_t)bh*65536;
  const float* xv_g = xvt + (size_t)bh*65536;
  const float* eta_g = eta + (size_t)bh*1024;

  for (int i=t; i<16384; i+=512){
    W1[i] = W1in[h*16384+i];
    W2[i] = W2in[h*16384+i];
  }
  if (t<256) b1_s[t] = b1in[h*256+t];
  if (t<64)  b2_s[t] = b2in[h*64+t];
  float gwd = nw[h*64+lane];
  float gbd = nb[h*64+lane];

  int mt = w>>1;             // m-tile (rows mt*16..+15) for M=64 phases
  int nh = (w&1)*8;          // n-tile base (of 16) for N=256 phases
  int nh4 = (w&1)*2;         // n-tile base (of 4) for N=64 phases

  for (int n=0;n<16;n++){
    __syncthreads();
    // ---- stage chunk inputs ----
    for (int i=t;i<4096;i+=512){
      int r=i>>6, d=i&63;
      xq_s[r*72+d] = fbf(xq_g[n*4096+i]);
      xk_s[r*72+d] = fbf(xk_g[n*4096+i]);
    }
    if (t<64) eta_s[t] = eta_g[n*64+t];
    __syncthreads();

    // ---- P1: Z1 = xk@W1 + b1 ; X2=gelu, G1=gelu' ----
    {
      v4f acc[8];
      #pragma unroll
      for (int i=0;i<8;i++){ v4f z={0.f,0.f,0.f,0.f}; acc[i]=z; }
      #pragma unroll
      for (int kt=0;kt<2;kt++){
        v8s af = *(const v8s*)&xk_s[(mt*16+l16)*72 + kt*32 + q*8];
        #pragma unroll
        for (int nt=0;nt<8;nt++){
          int nb0 = (nh+nt)*16 + l16;
          v8s bf;
          #pragma unroll
          for (int j=0;j<8;j++) bf[j] = (short)fbf(W1[(kt*32+q*8+j)*256 + nb0]);
          acc[nt] = __builtin_amdgcn_mfma_f32_16x16x32_bf16(af, bf, acc[nt], 0,0,0);
        }
      }
      #pragma unroll
      for (int nt=0;nt<8;nt++){
        int col = (nh+nt)*16 + l16;
        float bb = b1_s[col];
        #pragma unroll
        for (int r=0;r<4;r++){
          int row = mt*16 + q*4 + r;
          float z = clampv(acc[nt][r] + bb);
          X2_s[row*264+col] = fbf(clampv(gelu_f(z)));
          GX_s[row*264+col] = fbf(clampv(gelu_bwd_f(z)));
        }
      }
    }
    __syncthreads();
    // ---- P2: Z2 = X2@W2 + b2 -> Zs ----
    {
      v4f acc[2];
      #pragma unroll
      for (int i=0;i<2;i++){ v4f z={0.f,0.f,0.f,0.f}; acc[i]=z; }
      #pragma unroll
      for (int kt=0;kt<8;kt++){
        v8s af = *(const v8s*)&X2_s[(mt*16+l16)*264 + kt*32 + q*8];
        #pragma unroll
        for (int nt=0;nt<2;nt++){
          int nb0 = (nh4+nt)*16 + l16;
          v8s bf;
          #pragma unroll
          for (int j=0;j<8;j++) bf[j] = (short)fbf(W2[(kt*32+q*8+j)*64 + nb0]);
          acc[nt] = __builtin_amdgcn_mfma_f32_16x16x32_bf16(af, bf, acc[nt], 0,0,0);
        }
      }
      #pragma unroll
      for (int nt=0;nt<2;nt++){
        int col=(nh4+nt)*16+l16;
        float bb=b2_s[col];
        #pragma unroll
        for (int r=0;r<4;r++) Zs[(mt*16+q*4+r)*68+col] = clampv(acc[nt][r]+bb);
      }
    }
    __syncthreads();
    // ---- LN2: gZ2 = ln_l2_bwd(Z2, xv-xk) ----
    #pragma unroll 1
    for (int i=0;i<8;i++){
      int row = w*8+i;
      float zz = Zs[row*68+lane];
      float mu = wsum(zz)*(1.f/64.f);
      float xm = zz-mu;
      float var = wsum(xm*xm)*(1.f/64.f);
      float stdv = sqrtf(var+1e-6f);
      float xh = xm/stdv;
      float tgt = xv_g[n*4096 + row*64 + lane] - bfu(xk_s[row*72+lane]);
      float gh = (gwd*xh + gbd - tgt)*gwd;
      float s1 = wsum(gh), s2 = wsum(gh*xh);
      gZ2_s[row*72+lane] = fbf(clampv((64.f*gh - s1 - xh*s2)/(64.f*stdv)));
    }
    __syncthreads();
    // ---- P3: gZ1 = (gZ2@W2^T) * G1 ----
    {
      v4f acc[8];
      #pragma unroll
      for (int i=0;i<8;i++){ v4f z={0.f,0.f,0.f,0.f}; acc[i]=z; }
      #pragma unroll
      for (int kt=0;kt<2;kt++){
        v8s af = *(const v8s*)&gZ2_s[(mt*16+l16)*72 + kt*32 + q*8];
        #pragma unroll
        for (int nt=0;nt<8;nt++){
          int nb0=(nh+nt)*16+l16;
          const float4 wa = *(const float4*)&W2[nb0*64 + kt*32 + q*8];
          const float4 wb = *(const float4*)&W2[nb0*64 + kt*32 + q*8 + 4];
          v8s bf;
          bf[0]=(short)fbf(wa.x); bf[1]=(short)fbf(wa.y); bf[2]=(short)fbf(wa.z); bf[3]=(short)fbf(wa.w);
          bf[4]=(short)fbf(wb.x); bf[5]=(short)fbf(wb.y); bf[6]=(short)fbf(wb.z); bf[7]=(short)fbf(wb.w);
          acc[nt] = __builtin_amdgcn_mfma_f32_16x16x32_bf16(af, bf, acc[nt], 0,0,0);
        }
      }
      #pragma unroll
      for (int nt=0;nt<8;nt++){
        int col=(nh+nt)*16+l16;
        #pragma unroll
        for (int r=0;r<4;r++){
          int row=mt*16+q*4+r;
          gZ1_s[row*264+col] = fbf(clampv(acc[nt][r]*bfu(GX_s[row*264+col])));
        }
      }
    }
    __syncthreads();
    // ---- P4: Am = -tril(eta_j*(xq@xk^T + 1)) ----
    {
      v4f acc[2];
      #pragma unroll
      for (int i=0;i<2;i++){ v4f z={0.f,0.f,0.f,0.f}; acc[i]=z; }
      #pragma unroll
      for (int kt=0;kt<2;kt++){
        v8s af = *(const v8s*)&xq_s[(mt*16+l16)*72+kt*32+q*8];
        #pragma unroll
        for (int nt=0;nt<2;nt++){
          v8s bf = *(const v8s*)&xk_s[((nh4+nt)*16+l16)*72+kt*32+q*8];
          acc[nt] = __builtin_amdgcn_mfma_f32_16x16x32_bf16(af, bf, acc[nt], 0,0,0);
        }
      }
      #pragma unroll
      for (int nt=0;nt<2;nt++){
        int col=(nh4+nt)*16+l16;
        float ec = eta_s[col];
        #pragma unroll
        for (int r=0;r<4;r++){
          int row=mt*16+q*4+r;
          Am_s[row*72+col] = (col<=row) ? fbf(-ec*(acc[nt][r]+1.f)) : (unsigned short)0;
        }
      }
    }
    __syncthreads();
    // ---- P5: Z1b = xq@W1 + b1 + Am@gZ1 ; X2b = gelu -> GX slot ----
    {
      v4f acc[8];
      #pragma unroll
      for (int i=0;i<8;i++){ v4f z={0.f,0.f,0.f,0.f}; acc[i]=z; }
      #pragma unroll
      for (int kt=0;kt<2;kt++){
        v8s af = *(const v8s*)&xq_s[(mt*16+l16)*72+kt*32+q*8];
        #pragma unroll
        for (int nt=0;nt<8;nt++){
          int nb0=(nh+nt)*16+l16;
          v8s bf;
          #pragma unroll
          for (int j=0;j<8;j++) bf[j] = (short)fbf(W1[(kt*32+q*8+j)*256 + nb0]);
          acc[nt] = __builtin_amdgcn_mfma_f32_16x16x32_bf16(af, bf, acc[nt], 0,0,0);
        }
      }
      #pragma unroll
      for (int kt=0;kt<2;kt++){
        v8s af = *(const v8s*)&Am_s[(mt*16+l16)*72+kt*32+q*8];
        #pragma unroll
        for (int nt=0;nt<8;nt++){
          int nb0=(nh+nt)*16+l16;
          v8s bf;
          #pragma unroll
          for (int j=0;j<8;j++) bf[j] = (short)gZ1_s[(kt*32+q*8+j)*264 + nb0];
          acc[nt] = __builtin_amdgcn_mfma_f32_16x16x32_bf16(af, bf, acc[nt], 0,0,0);
        }
      }
      __syncthreads();   // GX (G1) fully consumed at P3; safe to overwrite after all waves pass P5 MFMAs? (G1 unused here; barrier guards X2b write vs nothing—kept for order)
      #pragma unroll
      for (int nt=0;nt<8;nt++){
        int col=(nh+nt)*16+l16;
        float bb=b1_s[col];
        #pragma unroll
        for (int r=0;r<4;r++){
          int row=mt*16+q*4+r;
          float z = clampv(acc[nt][r]+bb);
          GX_s[row*264+col] = fbf(clampv(gelu_f(z)));
        }
      }
    }
    __syncthreads();
    // ---- P6: Am = -tril(eta_j*(X2b@X2^T + 1)) ----
    {
      v4f acc[2];
      #pragma unroll
      for (int i=0;i<2;i++){ v4f z={0.f,0.f,0.f,0.f}; acc[i]=z; }
      #pragma unroll
      for (int kt=0;kt<8;kt++){
        v8s af = *(const v8s*)&GX_s[(mt*16+l16)*264+kt*32+q*8];
        #pragma unroll
        for (int nt=0;nt<2;nt++){
          v8s bf = *(const v8s*)&X2_s[((nh4+nt)*16+l16)*264+kt*32+q*8];
          acc[nt] = __builtin_amdgcn_mfma_f32_16x16x32_bf16(af, bf, acc[nt], 0,0,0);
        }
      }
      __syncthreads();  // Am read by no one now (P5 done); order write after P5's reads
      #pragma unroll
      for (int nt=0;nt<2;nt++){
        int col=(nh4+nt)*16+l16;
        float ec = eta_s[col];
        #pragma unroll
        for (int r=0;r<4;r++){
          int row=mt*16+q*4+r;
          Am_s[row*72+col] = (col<=row) ? fbf(-ec*(acc[nt][r]+1.f)) : (unsigned short)0;
        }
      }
    }
    __syncthreads();
    // ---- P7: Z2b = X2b@W2 + b2 + Am@gZ2 -> Zs ----
    {
      v4f acc[2];
      #pragma unroll
      for (int i=0;i<2;i++){ v4f z={0.f,0.f,0.f,0.f}; acc[i]=z; }
      #pragma unroll
      for (int kt=0;kt<8;kt++){
        v8s af = *(const v8s*)&GX_s[(mt*16+l16)*264+kt*32+q*8];
        #pragma unroll
        for (int nt=0;nt<2;nt++){
          int nb0=(nh4+nt)*16+l16;
          v8s bf;
          #pragma unroll
          for (int j=0;j<8;j++) bf[j] = (short)fbf(W2[(kt*32+q*8+j)*64 + nb0]);
          acc[nt] = __builtin_amdgcn_mfma_f32_16x16x32_bf16(af, bf, acc[nt], 0,0,0);
        }
      }
      #pragma unroll
      for (int kt=0;kt<2;kt++){
        v8s af = *(const v8s*)&Am_s[(mt*16+l16)*72+kt*32+q*8];
        #pragma unroll
        for (int nt=0;nt<2;nt++){
          int nb0=(nh4+nt)*16+l16;
          v8s bf;
          #pragma unroll
          for (int j=0;j<8;j++) bf[j] = (short)gZ2_s[(kt*32+q*8+j)*72 + nb0];
          acc[nt] = __builtin_amdgcn_mfma_f32_16x16x32_bf16(af, bf, acc[nt], 0,0,0);
        }
      }
      #pragma unroll
      for (int nt=0;nt<2;nt++){
        int col=(nh4+nt)*16+l16;
        float bb=b2_s[col];
        #pragma unroll
        for (int r=0;r<4;r++) Zs[(mt*16+q*4+r)*68+col] = clampv(acc[nt][r]+bb);
      }
    }
    __syncthreads();
    // ---- LN7: out = xq + LN(Z2b)*gw + gb -> tout ----
    #pragma unroll 1
    for (int i=0;i<8;i++){
      int row = w*8+i;
      float zz = Zs[row*68+lane];
      float mu = wsum(zz)*(1.f/64.f);
      float xm = zz-mu;
      float var = wsum(xm*xm)*(1.f/64.f);
      float xh = xm*rsqrtf(var+1e-6f);
      float outv = bfu(xq_s[row*72+lane]) + xh*gwd + gbd;
      tout[((size_t)(b*1024 + n*64 + row))*1024 + h*64 + lane] = outv;
    }
    // ---- H1: W1 -= (eta xk)^T @ gZ1 ; b1 -= colsum(eta gZ1) ----
    {
      v4f acc[8];
      #pragma unroll
      for (int i=0;i<8;i++){ v4f z={0.f,0.f,0.f,0.f}; acc[i]=z; }
      #pragma unroll
      for (int kt=0;kt<2;kt++){
        v8s af;
        #pragma unroll
        for (int j=0;j<8;j++){
          int jj = kt*32+q*8+j;
          af[j] = (short)fbf(eta_s[jj]*bfu(xk_s[jj*72 + mt*16+l16]));
        }
        #pragma unroll
        for (int nt=0;nt<8;nt++){
          int nb0=(nh+nt)*16+l16;
          v8s bf;
          #pragma unroll
          for (int j=0;j<8;j++) bf[j] = (short)gZ1_s[(kt*32+q*8+j)*264 + nb0];
          acc[nt] = __builtin_amdgcn_mfma_f32_16x16x32_bf16(af, bf, acc[nt], 0,0,0);
        }
      }
      #pragma unroll
      for (int nt=0;nt<8;nt++){
        int col=(nh+nt)*16+l16;
        #pragma unroll
        for (int r=0;r<4;r++){
          int krow=mt*16+q*4+r;
          W1[krow*256+col] -= acc[nt][r];
        }
      }
      if (t<256){
        float s=0.f;
        #pragma unroll 1
        for (int j=0;j<64;j++) s += eta_s[j]*bfu(gZ1_s[j*264+t]);
        b1_s[t] -= s;
      }
    }
    // ---- H2: W2 -= (eta X2)^T @ gZ2 ; b2 -= colsum(eta gZ2) ----
    {
      v4f acc[2][4];
      #pragma unroll
      for (int a=0;a<2;a++)
        #pragma unroll
        for (int c=0;c<4;c++){ v4f z={0.f,0.f,0.f,0.f}; acc[a][c]=z; }
      #pragma unroll
      for (int mi=0;mi<2;mi++){
        int mt2 = w*2+mi;  // 16 m-tiles over the 256 k-dim of W2
        #pragma unroll
        for (int kt=0;kt<2;kt++){
          v8s af;
          #pragma unroll
          for (int j=0;j<8;j++){
            int jj = kt*32+q*8+j;
            af[j] = (short)fbf(eta_s[jj]*bfu(X2_s[jj*264 + mt2*16+l16]));
          }
          #pragma unroll
          for (int nt=0;nt<4;nt++){
            v8s bf;
            #pragma unroll
            for (int j=0;j<8;j++) bf[j] = (short)gZ2_s[(kt*32+q*8+j)*72 + nt*16+l16];
            acc[mi][nt] = __builtin_amdgcn_mfma_f32_16x16x32_bf16(af, bf, acc[mi][nt], 0,0,0);
          }
        }
      }
      #pragma unroll
      for (int mi=0;mi<2;mi++){
        int mt2 = w*2+mi;
        #pragma unroll
        for (int nt=0;nt<4;nt++){
          int col=nt*16+l16;
          #pragma unroll
          for (int r=0;r<4;r++){
            int krow=mt2*16+q*4+r;
            W2[krow*64+col] -= acc[mi][nt][r];
          }
        }
      }
      if (t<64){
        float s=0.f;
        #pragma unroll 1
        for (int j=0;j<64;j++) s += eta_s[j]*bfu(gZ2_s[j*72+t]);
        b2_s[t] -= s;
      }
    }
  }
}

extern "C" void kernel_launch(void* const* d_in, const int* in_sizes, int n_in,
                              void* d_out, int out_size, void* d_ws, size_t ws_size,
                              hipStream_t stream)
{
  const float* x_in   = (const float*)d_in[0];
  const float* ln1w   = (const float*)d_in[1];
  const float* ln1b   = (const float*)d_in[2];
  const float* awq    = (const float*)d_in[3];
  const float* awk    = (const float*)d_in[4];
  const float* awv    = (const float*)d_in[5];
  const float* awo    = (const float*)d_in[6];
  const float* wqw    = (const float*)d_in[7];
  const float* wqb    = (const float*)d_in[8];
  const float* wkw    = (const float*)d_in[9];
  const float* wkb    = (const float*)d_in[10];
  const float* wvw    = (const float*)d_in[11];
  const float* wvb    = (const float*)d_in[12];
  const float* wow    = (const float*)d_in[13];
  const float* wob    = (const float*)d_in[14];
  const float* W1in   = (const float*)d_in[15];
  const float* b1in   = (const float*)d_in[16];
  const float* W2in   = (const float*)d_in[17];
  const float* b2in   = (const float*)d_in[18];
  const float* tnw    = (const float*)d_in[19];
  const float* tnb    = (const float*)d_in[20];
  const float* lrw    = (const float*)d_in[21];
  const float* lrb    = (const float*)d_in[22];
  const float* pnw    = (const float*)d_in[23];
  const float* pnb    = (const float*)d_in[24];
  const float* galpha = (const float*)d_in[25];
  float* outp = (float*)d_out;
  char* ws = (char*)d_ws;
  const size_t MB = (size_t)1<<20;
  float* bq  = (float*)(ws + 0*MB);
  float* bk  = (float*)(ws + 16*MB);
  float* bv  = (float*)(ws + 32*MB);
  float* bhh = (float*)(ws + 48*MB);
  float* bo  = (float*)(ws + 64*MB);
  float* bxb = (float*)(ws + 80*MB);
  float* xqt = (float*)(ws + 96*MB);
  float* xkt = (float*)(ws + 112*MB);
  float* xvt = (float*)(ws + 128*MB);
  float* eta  = (float*)(ws + 144*MB);
  float* W1g  = (float*)(ws + 36*MB);   // overlays bv (dead after xqkv)
  float* W2g  = (float*)(ws + 40*MB);
  float* tout = bo;                     // overlays bo (dead after wo-gemm)
  float* bhh2 = bhh;

  dim3 gg(8,32);
  ln_kernel<<<4096,256,0,stream>>>(x_in, ln1w, ln1b, bhh);
  gemm_kernel<<<gg,256,0,stream>>>(bhh, awq, nullptr, nullptr, nullptr, bq);
  gemm_kernel<<<gg,256,0,stream>>>(bhh, awk, nullptr, nullptr, nullptr, bk);
  gemm_kernel<<<gg,256,0,stream>>>(bhh, awv, nullptr, nullptr, nullptr, bv);
  attn_kernel<<<1024,256,0,stream>>>(bq,bk,bv,bo);
  gemm_kernel<<<gg,256,0,stream>>>(bo, awo, nullptr, x_in, nullptr, bxb);
  gemm_kernel<<<gg,256,0,stream>>>(bxb, wqw, wqb, nullptr, nullptr, bq);
  gemm_kernel<<<gg,256,0,stream>>>(bxb, wkw, wkb, nullptr, nullptr, bk);
  gemm_kernel<<<gg,256,0,stream>>>(bxb, wvw, wvb, nullptr, nullptr, bv);
  xqkv_kernel<<<16384,256,0,stream>>>(bq,bk,bv,tnw,tnb,xqt,xkt,xvt);
  eta_kernel<<<1024,256,0,stream>>>(bxb, lrw, lrb, eta);
  scan_kernel<<<64,512,0,stream>>>(xqt,xkt,xvt,eta,W1in,b1in,W2in,b2in,tnw,tnb,
                                   W1g,W2g,tout);
  ln_kernel<<<4096,256,0,stream>>>(tout, pnw, pnb, bhh2);
  gemm_kernel<<<gg,256,0,stream>>>(bhh2, wow, wob, bxb, galpha, outp);
}

// Round 5
// 1996.772 us; speedup vs baseline: 4.4953x; 2.7540x over previous
//
#include <hip/hip_runtime.h>

// Shapes (fixed): B=4 S=1024 D=1024 H=16 HD=64 C=64 NC=16 DFF=256
// All external I/O and inter-kernel buffers are float32 (per reference dtypes).
typedef short v8s __attribute__((ext_vector_type(8)));
typedef short v4s __attribute__((ext_vector_type(4)));
typedef float v4f __attribute__((ext_vector_type(4)));

__device__ __forceinline__ float bfu(unsigned short u){ return __uint_as_float(((unsigned)u)<<16); }
__device__ __forceinline__ unsigned short fbf(float f){
  unsigned u = __float_as_uint(f);
  u += 0x7fffu + ((u>>16)&1u);
  return (unsigned short)(u>>16);
}
__device__ __forceinline__ float wsum(float v){
  #pragma unroll
  for (int off=32; off>0; off>>=1) v += __shfl_xor(v, off, 64);
  return v;
}
__device__ __forceinline__ float wmaxf(float v){
  #pragma unroll
  for (int off=32; off>0; off>>=1) v = fmaxf(v, __shfl_xor(v, off, 64));
  return v;
}
__device__ __forceinline__ float clampv(float x){ return fminf(fmaxf(x, -1e8f), 1e8f); }
__device__ __forceinline__ float tanh_f(float x){
  x = fminf(fmaxf(x, -15.f), 15.f);
  float e = __expf(2.f*x);
  return (e-1.f)/(e+1.f);
}
__device__ __forceinline__ float gelu_f(float x){
  float t = tanh_f(0.79788456f*(x + 0.044715f*x*x*x));
  return 0.5f*x*(1.f+t);
}
__device__ __forceinline__ float gelu_bwd_f(float x){
  float t = tanh_f(0.79788456f*(x + 0.044715f*x*x*x));
  return 0.5f*x*(1.f-t*t)*(0.79788456f + 0.1070322243f*x*x) + 0.5f*(1.f+t);
}
// 8 contiguous bf16 from LDS (8B-aligned rows)
__device__ __forceinline__ v8s ld8(const unsigned short* p){
  v4s lo = *(const v4s*)p, hi = *(const v4s*)(p+4);
  v8s r;
  r[0]=lo[0];r[1]=lo[1];r[2]=lo[2];r[3]=lo[3];
  r[4]=hi[0];r[5]=hi[1];r[6]=hi[2];r[7]=hi[3];
  return r;
}
// 8 contiguous f32 from global -> bf16 frag
__device__ __forceinline__ v8s cv8(const float* p){
  float4 a=*(const float4*)p, b=*(const float4*)(p+4);
  v8s r;
  r[0]=(short)fbf(a.x); r[1]=(short)fbf(a.y); r[2]=(short)fbf(a.z); r[3]=(short)fbf(a.w);
  r[4]=(short)fbf(b.x); r[5]=(short)fbf(b.y); r[6]=(short)fbf(b.z); r[7]=(short)fbf(b.w);
  return r;
}

// ---------------- LayerNorm over D=1024, one block per row ----------------
__global__ __launch_bounds__(256) void ln_kernel(
    const float* __restrict__ X, const float* __restrict__ g,
    const float* __restrict__ bta, float* __restrict__ out)
{
  __shared__ float red[4];
  int row = blockIdx.x, t = threadIdx.x;
  const float* xr = X + (size_t)row*1024;
  float v[4];
  #pragma unroll
  for (int i=0;i<4;i++) v[i] = xr[t + i*256];
  float s = v[0]+v[1]+v[2]+v[3];
  s = wsum(s);
  if ((t&63)==0) red[t>>6]=s;
  __syncthreads();
  float mu = (red[0]+red[1]+red[2]+red[3])*(1.f/1024.f);
  float q=0.f;
  #pragma unroll
  for (int i=0;i<4;i++){ float dd=v[i]-mu; q+=dd*dd; }
  q = wsum(q);
  __syncthreads();
  if ((t&63)==0) red[t>>6]=q;
  __syncthreads();
  float var = (red[0]+red[1]+red[2]+red[3])*(1.f/1024.f);
  float rs = rsqrtf(var+1e-6f);
  #pragma unroll
  for (int i=0;i<4;i++){
    int c = t+i*256;
    out[(size_t)row*1024+c] = (v[i]-mu)*rs*g[c] + bta[c];
  }
}

// ---- MFMA GEMM: out[m,n] = gate(n)*(A[4096,1024]@Bw[1024,1024]^T + bias(n)) + res[m,n]
__global__ __launch_bounds__(256) void gemm_kernel(
    const float* __restrict__ A, const float* __restrict__ Bw,
    const float* __restrict__ bias, const float* __restrict__ res,
    const float* __restrict__ gate, float* __restrict__ out)
{
  __shared__ __attribute__((aligned(16))) short a_lds[128*40];
  __shared__ __attribute__((aligned(16))) short b_lds[128*40];
  int t=threadIdx.x, w=t>>6, lane=t&63;
  int gm = blockIdx.y*128, gn = blockIdx.x*128;
  int wm = (w>>1)*64, wn = (w&1)*64;
  int lr = lane&15, lk = (lane>>4)*8;
  v4f acc[4][4];
  #pragma unroll
  for (int i=0;i<4;i++)
    #pragma unroll
    for (int j=0;j<4;j++){ v4f z = {0.f,0.f,0.f,0.f}; acc[i][j]=z; }
  for (int kk=0; kk<1024; kk+=32){
    __syncthreads();
    #pragma unroll
    for (int pass=0;pass<4;pass++){
      int slot=t+pass*256, row=slot>>3, c4=(slot&7)*4;
      float4 av = *(const float4*)&A[(size_t)(gm+row)*1024 + kk + c4];
      float4 bv = *(const float4*)&Bw[(size_t)(gn+row)*1024 + kk + c4];
      v4s at, bt;
      at[0]=(short)fbf(av.x); at[1]=(short)fbf(av.y); at[2]=(short)fbf(av.z); at[3]=(short)fbf(av.w);
      bt[0]=(short)fbf(bv.x); bt[1]=(short)fbf(bv.y); bt[2]=(short)fbf(bv.z); bt[3]=(short)fbf(bv.w);
      *(v4s*)&a_lds[row*40+c4] = at;
      *(v4s*)&b_lds[row*40+c4] = bt;
    }
    __syncthreads();
    v8s af[4], bfr[4];
    #pragma unroll
    for (int i=0;i<4;i++) af[i] = *(const v8s*)&a_lds[(wm+i*16+lr)*40+lk];
    #pragma unroll
    for (int j=0;j<4;j++) bfr[j] = *(const v8s*)&b_lds[(wn+j*16+lr)*40+lk];
    #pragma unroll
    for (int i=0;i<4;i++)
      #pragma unroll
      for (int j=0;j<4;j++)
        acc[i][j] = __builtin_amdgcn_mfma_f32_16x16x32_bf16(af[i], bfr[j], acc[i][j], 0,0,0);
  }
  int quad = lane>>4;
  #pragma unroll
  for (int j=0;j<4;j++){
    int gc = gn + wn + j*16 + lr;
    float bval = bias ? bias[gc] : 0.f;
    float gval = gate ? tanh_f(gate[gc]) : 1.f;
    #pragma unroll
    for (int i=0;i<4;i++){
      #pragma unroll
      for (int r=0;r<4;r++){
        int grow = gm + wm + i*16 + quad*4 + r;
        float v = (acc[i][j][r] + bval)*gval;
        if (res) v += res[(size_t)grow*1024 + gc];
        out[(size_t)grow*1024 + gc] = v;
      }
    }
  }
}

// ---------------- Flash attention, block = (b,h,q-tile of 64) ----------------
__global__ __launch_bounds__(256) void attn_kernel(
    const float* __restrict__ Q, const float* __restrict__ K,
    const float* __restrict__ V, float* __restrict__ O)
{
  __shared__ __attribute__((aligned(16))) float q_lds[64*68];
  __shared__ __attribute__((aligned(16))) float k_lds[64*68];
  __shared__ __attribute__((aligned(16))) float v_lds[64*68];
  __shared__ __attribute__((aligned(16))) float p_lds[4][16][64];
  int t=threadIdx.x, w=t>>6, lane=t&63;
  int qt = blockIdx.x & 15, bh = blockIdx.x >> 4;
  int b = bh >> 4, h = bh & 15;
  const size_t base = ((size_t)b*1024)*1024 + (size_t)h*64;
  #pragma unroll
  for (int pass=0;pass<4;pass++){
    int slot=t+pass*256, row=slot>>4, c4=(slot&15)*4;
    *(float4*)&q_lds[row*68+c4] = *(const float4*)&Q[base + (size_t)(qt*64+row)*1024 + c4];
  }
  float mi[16], li[16], o[16], al[16];
  #pragma unroll
  for (int i=0;i<16;i++){ mi[i]=-1e30f; li[i]=0.f; o[i]=0.f; al[i]=0.f; }
  for (int kt=0; kt<=qt; kt++){
    __syncthreads();
    #pragma unroll
    for (int pass=0;pass<4;pass++){
      int slot=t+pass*256, row=slot>>4, c4=(slot&15)*4;
      *(float4*)&k_lds[row*68+c4] = *(const float4*)&K[base + (size_t)(kt*64+row)*1024 + c4];
      *(float4*)&v_lds[row*68+c4] = *(const float4*)&V[base + (size_t)(kt*64+row)*1024 + c4];
    }
    __syncthreads();
    #pragma unroll 1
    for (int i=0;i<16;i++){
      int r=w*16+i, sq=qt*64+r;
      float s=0.f;
      #pragma unroll
      for (int d4=0;d4<16;d4++){
        const float4 q4 = *(const float4*)&q_lds[r*68+d4*4];
        const float4 k4 = *(const float4*)&k_lds[lane*68+d4*4];
        s += q4.x*k4.x + q4.y*k4.y + q4.z*k4.z + q4.w*k4.w;
      }
      s *= 0.125f;
      bool ok = (kt*64+lane) <= sq;
      float sm = ok ? s : -1e30f;
      float mx = wmaxf(sm);
      float mnew = fmaxf(mi[i], mx);
      float aexp = __expf(mi[i]-mnew);
      float p = ok ? __expf(s-mnew) : 0.f;
      float ps = wsum(p);
      li[i] = li[i]*aexp + ps;
      mi[i] = mnew;
      al[i] = aexp;
      p_lds[w][i][lane] = p;
    }
    __syncthreads();
    #pragma unroll 1
    for (int i=0;i<16;i++){
      float acc = o[i]*al[i];
      #pragma unroll
      for (int j4=0;j4<16;j4++){
        const float4 p4 = *(const float4*)&p_lds[w][i][j4*4];
        acc += p4.x*v_lds[(j4*4+0)*68+lane]
             + p4.y*v_lds[(j4*4+1)*68+lane]
             + p4.z*v_lds[(j4*4+2)*68+lane]
             + p4.w*v_lds[(j4*4+3)*68+lane];
      }
      o[i]=acc;
    }
  }
  #pragma unroll
  for (int i=0;i<16;i++){
    int r=w*16+i;
    O[base + (size_t)(qt*64+r)*1024 + lane] = o[i]/li[i];
  }
}

// ------- XQ/XK normalize + XV fuse; write TTT layout [B,H,S,HD]. wave = (b,s,h) -------
__global__ __launch_bounds__(256) void xqkv_kernel(
    const float* __restrict__ XQ, const float* __restrict__ XK,
    const float* __restrict__ XV, const float* __restrict__ nw,
    const float* __restrict__ nb,
    float* __restrict__ xqt, float* __restrict__ xkt, float* __restrict__ xvt)
{
  int gw = (int)((blockIdx.x*256 + threadIdx.x)>>6);
  int lane = threadIdx.x & 63;
  int h = gw & 15, s = (gw>>4)&1023, b = gw>>14;
  size_t src = ((size_t)(b*1024+s))*1024 + h*64 + lane;
  float xq = XQ[src], xk = XK[src], xv = XV[src];
  float nq = sqrtf(wsum(xq*xq));
  float nk = sqrtf(wsum(xk*xk));
  float xqn = xq / fmaxf(nq, 1e-12f);
  float xkn = xk / fmaxf(nk, 1e-12f);
  float mu = wsum(xv)*(1.f/64.f);
  float xm = xv-mu;
  float var = wsum(xm*xm)*(1.f/64.f);
  float xvh = xm*rsqrtf(var+1e-6f);
  float xvn = nw[h*64+lane]*xvh + nb[h*64+lane] + xkn;
  size_t dst = ((size_t)(b*16+h)*1024 + s)*64 + lane;
  xqt[dst]=xqn; xkt[dst]=xkn; xvt[dst]=xvn;
}

// ------- eta[b,h,s] = sigmoid(x[b,s,:]·lr_w[h,:] + lr_b[h]) / 64. wave = (b,s) -------
__global__ __launch_bounds__(256) void eta_kernel(
    const float* __restrict__ Xb, const float* __restrict__ lrw,
    const float* __restrict__ lrb, float* __restrict__ eta)
{
  int gw = (int)((blockIdx.x*256 + threadIdx.x)>>6);
  int lane = threadIdx.x & 63;
  int s = gw & 1023, b = gw >> 10;
  const float* xrow = Xb + ((size_t)(b*1024+s))*1024;
  float xr[16];
  #pragma unroll
  for (int i=0;i<16;i++) xr[i] = xrow[i*64+lane];
  #pragma unroll 1
  for (int h=0;h<16;h++){
    const float* wr = lrw + h*1024;
    float acc=0.f;
    #pragma unroll
    for (int i=0;i<16;i++) acc += xr[i]*wr[i*64+lane];
    acc = wsum(acc);
    if (lane==h){
      float vv = acc + lrb[h];
      float sg = 1.f/(1.f+__expf(-vv));
      eta[((size_t)(b*16+h))*1024 + s] = sg*(1.f/64.f);
    }
  }
}

// ---------------- TTT scan (MFMA, LDS-resident): one 512-thread block per (b,h) ----------------
// W1/W2 masters live in f32 registers (H1/H2 C-frag layouts); bf16 LDS copies staged per chunk.
// MFMA 16x16x32 bf16 layouts: A/B frag m|n=lane&15, k=quad*8+j; C/D col=lane&15, row=quad*4+reg.
__global__ __launch_bounds__(512) void scan_kernel(
    const float* __restrict__ xqt, const float* __restrict__ xkt,
    const float* __restrict__ xvt, const float* __restrict__ eta,
    const float* __restrict__ W1in, const float* __restrict__ b1in,
    const float* __restrict__ W2in, const float* __restrict__ b2in,
    const float* __restrict__ nw, const float* __restrict__ nb,
    float* __restrict__ tout)
{
  __shared__ __attribute__((aligned(16))) unsigned short W1t[256*68]; // [n<256][k<64] (W1^T)
  __shared__ __attribute__((aligned(16))) unsigned short W2s[256*68]; // [k<256][d<64]
  __shared__ __attribute__((aligned(16))) unsigned short X2s[64*260]; // X2
  __shared__ __attribute__((aligned(16))) unsigned short GZ1[64*260]; // gZ1, then X2b
  __shared__ __attribute__((aligned(16))) unsigned short GZ2[64*68];
  __shared__ __attribute__((aligned(16))) unsigned short AMs[64*68];  // -tril(eta*(A+1))
  __shared__ float ln_scr[64*8];
  __shared__ float eta_s[64], b1_s[256], b2_s[64], nw_s[64], nb_s[64];

  const int t=threadIdx.x, w=t>>6, lane=t&63, q=lane>>4, l16=lane&15;
  const int bh=blockIdx.x, b=bh>>4, h=bh&15;
  const int mt=w>>1, nh=(w&1)*8, nh4=(w&1)*2;
  const float* xq_g = xqt + (size_t)bh*65536;
  const float* xk_g = xkt + (size_t)bh*65536;
  const float* xv_g = xvt + (size_t)bh*65536;
  const float* eta_g = eta + (size_t)bh*1024;

  // W1 master: rows k=mt*16+q*4+r, cols n=(nh+nt)*16+l16
  float w1r[8][4];
  #pragma unroll
  for (int nt=0;nt<8;nt++){
    int col=(nh+nt)*16+l16;
    #pragma unroll
    for (int r=0;r<4;r++) w1r[nt][r] = W1in[h*16384 + (mt*16+q*4+r)*256 + col];
  }
  // W2 master: rows k=(w*2+mi)*16+q*4+r, cols d=nt*16+l16
  float w2r[2][4][4];
  #pragma unroll
  for (int mi=0;mi<2;mi++)
    #pragma unroll
    for (int nt=0;nt<4;nt++){
      int col=nt*16+l16;
      #pragma unroll
      for (int r=0;r<4;r++) w2r[mi][nt][r] = W2in[h*16384 + ((w*2+mi)*16+q*4+r)*64 + col];
    }
  if (t<256) b1_s[t]=b1in[h*256+t];
  if (t<64){ b2_s[t]=b2in[h*64+t]; nw_s[t]=nw[h*64+t]; nb_s[t]=nb[h*64+t]; }

  for (int n=0;n<16;n++){
    __syncthreads();
    // ---- stage bf16 W copies from registers + eta ----
    #pragma unroll
    for (int nt=0;nt<8;nt++){
      int col=(nh+nt)*16+l16;
      #pragma unroll
      for (int pr=0;pr<2;pr++){
        unsigned lo=fbf(w1r[nt][pr*2]), hi=fbf(w1r[nt][pr*2+1]);
        *(unsigned*)&W1t[col*68 + mt*16+q*4 + pr*2] = lo | (hi<<16);
      }
    }
    #pragma unroll
    for (int mi=0;mi<2;mi++)
      #pragma unroll
      for (int nt=0;nt<4;nt++){
        int col=nt*16+l16;
        #pragma unroll
        for (int r=0;r<4;r++)
          W2s[((w*2+mi)*16+q*4+r)*68 + col] = fbf(w2r[mi][nt][r]);
      }
    if (t<64) eta_s[t]=eta_g[n*64+t];
    __syncthreads();

    // ---- P1: Z1 = xk@W1 + b1 (Z1 stays in regs a1); X2 = gelu -> X2s ----
    v4f a1[8];
    #pragma unroll
    for (int i=0;i<8;i++){ v4f z={0.f,0.f,0.f,0.f}; a1[i]=z; }
    #pragma unroll
    for (int kt=0;kt<2;kt++){
      v8s af = cv8(xk_g + n*4096 + (mt*16+l16)*64 + kt*32+q*8);
      #pragma unroll
      for (int nt=0;nt<8;nt++){
        v8s bf = ld8(&W1t[((nh+nt)*16+l16)*68 + kt*32+q*8]);
        a1[nt] = __builtin_amdgcn_mfma_f32_16x16x32_bf16(af, bf, a1[nt], 0,0,0);
      }
    }
    #pragma unroll
    for (int nt=0;nt<8;nt++){
      int col=(nh+nt)*16+l16; float bb=b1_s[col];
      #pragma unroll
      for (int r=0;r<4;r++){
        float z=clampv(a1[nt][r]+bb); a1[nt][r]=z;
        X2s[(mt*16+q*4+r)*260+col]=fbf(clampv(gelu_f(z)));
      }
    }
    __syncthreads();

    // ---- P2: Z2 = X2@W2 + b2 ; LN2 -> gZ2 (cross-wave reductions via ln_scr) ----
    {
      v4f a2[2];
      #pragma unroll
      for (int i=0;i<2;i++){ v4f z={0.f,0.f,0.f,0.f}; a2[i]=z; }
      #pragma unroll
      for (int kt=0;kt<8;kt++){
        v8s af = ld8(&X2s[(mt*16+l16)*260 + kt*32+q*8]);
        #pragma unroll
        for (int nt=0;nt<2;nt++){
          int nb0=(nh4+nt)*16+l16;
          v8s bf;
          #pragma unroll
          for (int j=0;j<8;j++) bf[j]=(short)W2s[(kt*32+q*8+j)*68+nb0];
          a2[nt] = __builtin_amdgcn_mfma_f32_16x16x32_bf16(af, bf, a2[nt], 0,0,0);
        }
      }
      float z2[2][4];
      #pragma unroll
      for (int nt=0;nt<2;nt++){
        float bb=b2_s[(nh4+nt)*16+l16];
        #pragma unroll
        for (int r=0;r<4;r++) z2[nt][r]=clampv(a2[nt][r]+bb);
      }
      #pragma unroll
      for (int r=0;r<4;r++){
        float s1v=z2[0][r]+z2[1][r];
        float s2v=z2[0][r]*z2[0][r]+z2[1][r]*z2[1][r];
        #pragma unroll
        for (int off=1;off<16;off<<=1){ s1v+=__shfl_xor(s1v,off,16); s2v+=__shfl_xor(s2v,off,16); }
        if (l16==0){ int row=mt*16+q*4+r; ln_scr[row*8+(w&1)]=s1v; ln_scr[row*8+2+(w&1)]=s2v; }
      }
      __syncthreads();
      float muv[4], istd[4];
      #pragma unroll
      for (int r=0;r<4;r++){
        int row=mt*16+q*4+r;
        float S1=ln_scr[row*8+0]+ln_scr[row*8+1];
        float S2=ln_scr[row*8+2]+ln_scr[row*8+3];
        float mu=S1*(1.f/64.f);
        float var=fmaxf(S2*(1.f/64.f)-mu*mu, 0.f);
        muv[r]=mu; istd[r]=rsqrtf(var+1e-6f);
      }
      float xh[2][4], gh[2][4];
      #pragma unroll
      for (int nt=0;nt<2;nt++){
        int col=(nh4+nt)*16+l16;
        float gw_=nw_s[col], gb_=nb_s[col];
        #pragma unroll
        for (int r=0;r<4;r++){
          int row=mt*16+q*4+r;
          float x_=(z2[nt][r]-muv[r])*istd[r];
          float tgt = xv_g[n*4096+row*64+col] - xk_g[n*4096+row*64+col];
          xh[nt][r]=x_;
          gh[nt][r]=(gw_*x_+gb_-tgt)*gw_;
        }
      }
      #pragma unroll
      for (int r=0;r<4;r++){
        float t1=gh[0][r]+gh[1][r];
        float t2=gh[0][r]*xh[0][r]+gh[1][r]*xh[1][r];
        #pragma unroll
        for (int off=1;off<16;off<<=1){ t1+=__shfl_xor(t1,off,16); t2+=__shfl_xor(t2,off,16); }
        if (l16==0){ int row=mt*16+q*4+r; ln_scr[row*8+4+(w&1)]=t1; ln_scr[row*8+6+(w&1)]=t2; }
      }
      __syncthreads();
      #pragma unroll
      for (int nt=0;nt<2;nt++){
        int col=(nh4+nt)*16+l16;
        #pragma unroll
        for (int r=0;r<4;r++){
          int row=mt*16+q*4+r;
          float G1s=ln_scr[row*8+4]+ln_scr[row*8+5];
          float G2s=ln_scr[row*8+6]+ln_scr[row*8+7];
          float gz=(64.f*gh[nt][r]-G1s-xh[nt][r]*G2s)*istd[r]*(1.f/64.f);
          GZ2[row*68+col]=fbf(clampv(gz));
        }
      }
    }
    __syncthreads();

    // ---- P3: gZ1 = (gZ2@W2^T) * gelu'(Z1regs) -> GZ1 ----
    {
      v4f a3[8];
      #pragma unroll
      for (int i=0;i<8;i++){ v4f z={0.f,0.f,0.f,0.f}; a3[i]=z; }
      #pragma unroll
      for (int kt=0;kt<2;kt++){
        v8s af = ld8(&GZ2[(mt*16+l16)*68 + kt*32+q*8]);
        #pragma unroll
        for (int nt=0;nt<8;nt++){
          v8s bf = ld8(&W2s[((nh+nt)*16+l16)*68 + kt*32+q*8]);
          a3[nt] = __builtin_amdgcn_mfma_f32_16x16x32_bf16(af, bf, a3[nt], 0,0,0);
        }
      }
      #pragma unroll
      for (int nt=0;nt<8;nt++){
        int col=(nh+nt)*16+l16;
        #pragma unroll
        for (int r=0;r<4;r++){
          float g=clampv(a3[nt][r]*gelu_bwd_f(a1[nt][r]));
          GZ1[(mt*16+q*4+r)*260+col]=fbf(g);
        }
      }
    }
    __syncthreads();

    // ---- P4: AMs = -tril(eta_j*(xq@xk^T + 1)) ; b1 colsum prefetch ----
    v8s xqf[2];
    float bacc=0.f;
    {
      v4f a4[2];
      #pragma unroll
      for (int i=0;i<2;i++){ v4f z={0.f,0.f,0.f,0.f}; a4[i]=z; }
      #pragma unroll
      for (int kt=0;kt<2;kt++){
        xqf[kt] = cv8(xq_g + n*4096 + (mt*16+l16)*64 + kt*32+q*8);
        #pragma unroll
        for (int nt=0;nt<2;nt++){
          v8s bf = cv8(xk_g + n*4096 + ((nh4+nt)*16+l16)*64 + kt*32+q*8);
          a4[nt] = __builtin_amdgcn_mfma_f32_16x16x32_bf16(xqf[kt], bf, a4[nt], 0,0,0);
        }
      }
      #pragma unroll
      for (int nt=0;nt<2;nt++){
        int col=(nh4+nt)*16+l16;
        float ec=eta_s[col];
        #pragma unroll
        for (int r=0;r<4;r++){
          int row=mt*16+q*4+r;
          AMs[row*68+col] = (col<=row) ? fbf(-ec*(a4[nt][r]+1.f)) : (unsigned short)0;
        }
      }
      if (t<256){
        #pragma unroll 1
        for (int j=0;j<64;j++) bacc += eta_s[j]*bfu(GZ1[j*260+t]);
      }
    }
    __syncthreads();

    // ---- P5: Z1b = xq@W1 + AMs@gZ1 + b1 ;  H1: W1regs -= (eta xk)^T @ gZ1 ----
    v4f a5[8];
    float bbold[8];
    {
      v4f a6[8];
      #pragma unroll
      for (int i=0;i<8;i++){ v4f z={0.f,0.f,0.f,0.f}; a5[i]=z; a6[i]=z; }
      #pragma unroll
      for (int nt=0;nt<8;nt++) bbold[nt]=b1_s[(nh+nt)*16+l16];
      #pragma unroll
      for (int kt=0;kt<2;kt++){
        #pragma unroll
        for (int nt=0;nt<8;nt++){
          v8s bf = ld8(&W1t[((nh+nt)*16+l16)*68 + kt*32+q*8]);
          a5[nt] = __builtin_amdgcn_mfma_f32_16x16x32_bf16(xqf[kt], bf, a5[nt], 0,0,0);
        }
      }
      #pragma unroll
      for (int kt=0;kt<2;kt++){
        v8s afA = ld8(&AMs[(mt*16+l16)*68 + kt*32+q*8]);
        v8s afE;
        #pragma unroll
        for (int j=0;j<8;j++){
          int jj=kt*32+q*8+j;
          afE[j]=(short)fbf(eta_s[jj]*xk_g[n*4096 + jj*64 + mt*16+l16]);
        }
        #pragma unroll
        for (int nt=0;nt<8;nt++){
          int nb0=(nh+nt)*16+l16;
          v8s bf;
          #pragma unroll
          for (int j=0;j<8;j++) bf[j]=(short)GZ1[(kt*32+q*8+j)*260+nb0];
          a5[nt] = __builtin_amdgcn_mfma_f32_16x16x32_bf16(afA, bf, a5[nt], 0,0,0);
          a6[nt] = __builtin_amdgcn_mfma_f32_16x16x32_bf16(afE, bf, a6[nt], 0,0,0);
        }
      }
      #pragma unroll
      for (int nt=0;nt<8;nt++)
        #pragma unroll
        for (int r=0;r<4;r++) w1r[nt][r] -= a6[nt][r];
    }
    __syncthreads();
    // ---- X2b = gelu(Z1b) -> GZ1 slot ; apply b1 update ----
    #pragma unroll
    for (int nt=0;nt<8;nt++){
      int col=(nh+nt)*16+l16;
      #pragma unroll
      for (int r=0;r<4;r++){
        float z=clampv(a5[nt][r]+bbold[nt]);
        GZ1[(mt*16+q*4+r)*260+col]=fbf(clampv(gelu_f(z)));
      }
    }
    if (t<256) b1_s[t] -= bacc;
    __syncthreads();

    // ---- P6: AMs = -tril(eta_j*(X2b@X2^T + 1)) ; b2 colsum prefetch ----
    float bacc2=0.f;
    {
      v4f a7[2];
      #pragma unroll
      for (int i=0;i<2;i++){ v4f z={0.f,0.f,0.f,0.f}; a7[i]=z; }
      #pragma unroll
      for (int kt=0;kt<8;kt++){
        v8s af = ld8(&GZ1[(mt*16+l16)*260 + kt*32+q*8]);   // X2b
        #pragma unroll
        for (int nt=0;nt<2;nt++){
          v8s bf = ld8(&X2s[((nh4+nt)*16+l16)*260 + kt*32+q*8]);
          a7[nt] = __builtin_amdgcn_mfma_f32_16x16x32_bf16(af, bf, a7[nt], 0,0,0);
        }
      }
      #pragma unroll
      for (int nt=0;nt<2;nt++){
        int col=(nh4+nt)*16+l16;
        float ec=eta_s[col];
        #pragma unroll
        for (int r=0;r<4;r++){
          int row=mt*16+q*4+r;
          AMs[row*68+col] = (col<=row) ? fbf(-ec*(a7[nt][r]+1.f)) : (unsigned short)0;
        }
      }
      if (t<64){
        #pragma unroll 1
        for (int j=0;j<64;j++) bacc2 += eta_s[j]*bfu(GZ2[j*68+t]);
      }
    }
    __syncthreads();

    // ---- P7: Z2b = X2b@W2 + AMs@gZ2 + b2 ; LN7 -> tout ; H2 ----
    {
      v4f a8[2];
      #pragma unroll
      for (int i=0;i<2;i++){ v4f z={0.f,0.f,0.f,0.f}; a8[i]=z; }
      float b2old[2];
      #pragma unroll
      for (int nt=0;nt<2;nt++) b2old[nt]=b2_s[(nh4+nt)*16+l16];
      #pragma unroll
      for (int kt=0;kt<8;kt++){
        v8s af = ld8(&GZ1[(mt*16+l16)*260 + kt*32+q*8]);   // X2b
        #pragma unroll
        for (int nt=0;nt<2;nt++){
          int nb0=(nh4+nt)*16+l16;
          v8s bf;
          #pragma unroll
          for (int j=0;j<8;j++) bf[j]=(short)W2s[(kt*32+q*8+j)*68+nb0];
          a8[nt] = __builtin_amdgcn_mfma_f32_16x16x32_bf16(af, bf, a8[nt], 0,0,0);
        }
      }
      #pragma unroll
      for (int kt=0;kt<2;kt++){
        v8s af = ld8(&AMs[(mt*16+l16)*68 + kt*32+q*8]);
        #pragma unroll
        for (int nt=0;nt<2;nt++){
          int nb0=(nh4+nt)*16+l16;
          v8s bf;
          #pragma unroll
          for (int j=0;j<8;j++) bf[j]=(short)GZ2[(kt*32+q*8+j)*68+nb0];
          a8[nt] = __builtin_amdgcn_mfma_f32_16x16x32_bf16(af, bf, a8[nt], 0,0,0);
        }
      }
      float z2b[2][4];
      #pragma unroll
      for (int nt=0;nt<2;nt++)
        #pragma unroll
        for (int r=0;r<4;r++) z2b[nt][r]=clampv(a8[nt][r]+b2old[nt]);
      #pragma unroll
      for (int r=0;r<4;r++){
        float s1v=z2b[0][r]+z2b[1][r];
        float s2v=z2b[0][r]*z2b[0][r]+z2b[1][r]*z2b[1][r];
        #pragma unroll
        for (int off=1;off<16;off<<=1){ s1v+=__shfl_xor(s1v,off,16); s2v+=__shfl_xor(s2v,off,16); }
        if (l16==0){ int row=mt*16+q*4+r; ln_scr[row*8+(w&1)]=s1v; ln_scr[row*8+2+(w&1)]=s2v; }
      }
      __syncthreads();
      #pragma unroll
      for (int r=0;r<4;r++){
        int row=mt*16+q*4+r;
        float S1=ln_scr[row*8+0]+ln_scr[row*8+1];
        float S2=ln_scr[row*8+2]+ln_scr[row*8+3];
        float mu=S1*(1.f/64.f);
        float var=fmaxf(S2*(1.f/64.f)-mu*mu, 0.f);
        float istd=rsqrtf(var+1e-6f);
        #pragma unroll
        for (int nt=0;nt<2;nt++){
          int col=(nh4+nt)*16+l16;
          float x_=(z2b[nt][r]-mu)*istd;
          float outv = xq_g[n*4096+row*64+col] + x_*nw_s[col] + nb_s[col];
          tout[((size_t)(b*1024 + n*64 + row))*1024 + h*64 + col] = outv;
        }
      }
      // H2: W2regs -= (eta X2)^T @ gZ2
      v4f a9[2][4];
      #pragma unroll
      for (int mi=0;mi<2;mi++)
        #pragma unroll
        for (int c=0;c<4;c++){ v4f z={0.f,0.f,0.f,0.f}; a9[mi][c]=z; }
      #pragma unroll
      for (int kt=0;kt<2;kt++){
        v8s bfs[4];
        #pragma unroll
        for (int nt=0;nt<4;nt++)
          #pragma unroll
          for (int j=0;j<8;j++) bfs[nt][j]=(short)GZ2[(kt*32+q*8+j)*68 + nt*16+l16];
        #pragma unroll
        for (int mi=0;mi<2;mi++){
          v8s af;
          #pragma unroll
          for (int j=0;j<8;j++){
            int jj=kt*32+q*8+j;
            af[j]=(short)fbf(eta_s[jj]*bfu(X2s[jj*260 + (w*2+mi)*16+l16]));
          }
          #pragma unroll
          for (int nt=0;nt<4;nt++)
            a9[mi][nt] = __builtin_amdgcn_mfma_f32_16x16x32_bf16(af, bfs[nt], a9[mi][nt], 0,0,0);
        }
      }
      #pragma unroll
      for (int mi=0;mi<2;mi++)
        #pragma unroll
        for (int nt=0;nt<4;nt++)
          #pragma unroll
          for (int r=0;r<4;r++) w2r[mi][nt][r] -= a9[mi][nt][r];
      if (t<64) b2_s[t] -= bacc2;
    }
  }
}

extern "C" void kernel_launch(void* const* d_in, const int* in_sizes, int n_in,
                              void* d_out, int out_size, void* d_ws, size_t ws_size,
                              hipStream_t stream)
{
  const float* x_in   = (const float*)d_in[0];
  const float* ln1w   = (const float*)d_in[1];
  const float* ln1b   = (const float*)d_in[2];
  const float* awq    = (const float*)d_in[3];
  const float* awk    = (const float*)d_in[4];
  const float* awv    = (const float*)d_in[5];
  const float* awo    = (const float*)d_in[6];
  const float* wqw    = (const float*)d_in[7];
  const float* wqb    = (const float*)d_in[8];
  const float* wkw    = (const float*)d_in[9];
  const float* wkb    = (const float*)d_in[10];
  const float* wvw    = (const float*)d_in[11];
  const float* wvb    = (const float*)d_in[12];
  const float* wow    = (const float*)d_in[13];
  const float* wob    = (const float*)d_in[14];
  const float* W1in   = (const float*)d_in[15];
  const float* b1in   = (const float*)d_in[16];
  const float* W2in   = (const float*)d_in[17];
  const float* b2in   = (const float*)d_in[18];
  const float* tnw    = (const float*)d_in[19];
  const float* tnb    = (const float*)d_in[20];
  const float* lrw    = (const float*)d_in[21];
  const float* lrb    = (const float*)d_in[22];
  const float* pnw    = (const float*)d_in[23];
  const float* pnb    = (const float*)d_in[24];
  const float* galpha = (const float*)d_in[25];
  float* outp = (float*)d_out;
  char* ws = (char*)d_ws;
  const size_t MB = (size_t)1<<20;
  float* bq  = (float*)(ws + 0*MB);
  float* bk  = (float*)(ws + 16*MB);
  float* bv  = (float*)(ws + 32*MB);
  float* bhh = (float*)(ws + 48*MB);
  float* bo  = (float*)(ws + 64*MB);
  float* bxb = (float*)(ws + 80*MB);
  float* xqt = (float*)(ws + 96*MB);
  float* xkt = (float*)(ws + 112*MB);
  float* xvt = (float*)(ws + 128*MB);
  float* eta  = (float*)(ws + 144*MB);
  float* tout = bo;                     // overlays bo (dead after wo-gemm)
  float* bhh2 = bhh;

  dim3 gg(8,32);
  ln_kernel<<<4096,256,0,stream>>>(x_in, ln1w, ln1b, bhh);
  gemm_kernel<<<gg,256,0,stream>>>(bhh, awq, nullptr, nullptr, nullptr, bq);
  gemm_kernel<<<gg,256,0,stream>>>(bhh, awk, nullptr, nullptr, nullptr, bk);
  gemm_kernel<<<gg,256,0,stream>>>(bhh, awv, nullptr, nullptr, nullptr, bv);
  attn_kernel<<<1024,256,0,stream>>>(bq,bk,bv,bo);
  gemm_kernel<<<gg,256,0,stream>>>(bo, awo, nullptr, x_in, nullptr, bxb);
  gemm_kernel<<<gg,256,0,stream>>>(bxb, wqw, wqb, nullptr, nullptr, bq);
  gemm_kernel<<<gg,256,0,stream>>>(bxb, wkw, wkb, nullptr, nullptr, bk);
  gemm_kernel<<<gg,256,0,stream>>>(bxb, wvw, wvb, nullptr, nullptr, bv);
  xqkv_kernel<<<16384,256,0,stream>>>(bq,bk,bv,tnw,tnb,xqt,xkt,xvt);
  eta_kernel<<<1024,256,0,stream>>>(bxb, lrw, lrb, eta);
  scan_kernel<<<64,512,0,stream>>>(xqt,xkt,xvt,eta,W1in,b1in,W2in,b2in,tnw,tnb,tout);
  ln_kernel<<<4096,256,0,stream>>>(tout, pnw, pnb, bhh2);
  gemm_kernel<<<gg,256,0,stream>>>(bhh2, wow, wob, bxb, galpha, outp);
}

// Round 6
// 1547.539 us; speedup vs baseline: 5.8002x; 1.2903x over previous
//
#include <hip/hip_runtime.h>

// Shapes (fixed): B=4 S=1024 D=1024 H=16 HD=64 C=64 NC=16 DFF=256
typedef short v8s __attribute__((ext_vector_type(8)));
typedef short v4s __attribute__((ext_vector_type(4)));
typedef float v4f __attribute__((ext_vector_type(4)));

__device__ __forceinline__ float bfu(unsigned short u){ return __uint_as_float(((unsigned)u)<<16); }
__device__ __forceinline__ unsigned short fbf(float f){
  unsigned u = __float_as_uint(f);
  u += 0x7fffu + ((u>>16)&1u);
  return (unsigned short)(u>>16);
}
__device__ __forceinline__ float wsum(float v){
  #pragma unroll
  for (int off=32; off>0; off>>=1) v += __shfl_xor(v, off, 64);
  return v;
}
__device__ __forceinline__ float clampv(float x){ return fminf(fmaxf(x, -1e8f), 1e8f); }
__device__ __forceinline__ float tanh_f(float x){
  x = fminf(fmaxf(x, -15.f), 15.f);
  float e = __expf(2.f*x);
  return (e-1.f)/(e+1.f);
}
__device__ __forceinline__ float gelu_f(float x){
  float t = tanh_f(0.79788456f*(x + 0.044715f*x*x*x));
  return 0.5f*x*(1.f+t);
}
__device__ __forceinline__ float gelu_bwd_f(float x){
  float t = tanh_f(0.79788456f*(x + 0.044715f*x*x*x));
  return 0.5f*x*(1.f-t*t)*(0.79788456f + 0.1070322243f*x*x) + 0.5f*(1.f+t);
}
__device__ __forceinline__ v8s ld8(const unsigned short* p){
  v4s lo = *(const v4s*)p, hi = *(const v4s*)(p+4);
  v8s r;
  r[0]=lo[0];r[1]=lo[1];r[2]=lo[2];r[3]=lo[3];
  r[4]=hi[0];r[5]=hi[1];r[6]=hi[2];r[7]=hi[3];
  return r;
}
__device__ __forceinline__ v8s cv8(const float* p){
  float4 a=*(const float4*)p, b=*(const float4*)(p+4);
  v8s r;
  r[0]=(short)fbf(a.x); r[1]=(short)fbf(a.y); r[2]=(short)fbf(a.z); r[3]=(short)fbf(a.w);
  r[4]=(short)fbf(b.x); r[5]=(short)fbf(b.y); r[6]=(short)fbf(b.z); r[7]=(short)fbf(b.w);
  return r;
}

// ---------------- LayerNorm over D=1024, one block per row ----------------
__global__ __launch_bounds__(256) void ln_kernel(
    const float* __restrict__ X, const float* __restrict__ g,
    const float* __restrict__ bta, float* __restrict__ out)
{
  __shared__ float red[4];
  int row = blockIdx.x, t = threadIdx.x;
  const float* xr = X + (size_t)row*1024;
  float v[4];
  #pragma unroll
  for (int i=0;i<4;i++) v[i] = xr[t + i*256];
  float s = v[0]+v[1]+v[2]+v[3];
  s = wsum(s);
  if ((t&63)==0) red[t>>6]=s;
  __syncthreads();
  float mu = (red[0]+red[1]+red[2]+red[3])*(1.f/1024.f);
  float q=0.f;
  #pragma unroll
  for (int i=0;i<4;i++){ float dd=v[i]-mu; q+=dd*dd; }
  q = wsum(q);
  __syncthreads();
  if ((t&63)==0) red[t>>6]=q;
  __syncthreads();
  float var = (red[0]+red[1]+red[2]+red[3])*(1.f/1024.f);
  float rs = rsqrtf(var+1e-6f);
  #pragma unroll
  for (int i=0;i<4;i++){
    int c = t+i*256;
    out[(size_t)row*1024+c] = (v[i]-mu)*rs*g[c] + bta[c];
  }
}

// ---- MFMA GEMM: out[m,n] = gate(n)*(A[4096,1024]@Bw[1024,1024]^T + bias(n)) + res[m,n]
__global__ __launch_bounds__(256) void gemm_kernel(
    const float* __restrict__ A, const float* __restrict__ Bw,
    const float* __restrict__ bias, const float* __restrict__ res,
    const float* __restrict__ gate, float* __restrict__ out)
{
  __shared__ __attribute__((aligned(16))) short a_lds[128*40];
  __shared__ __attribute__((aligned(16))) short b_lds[128*40];
  int t=threadIdx.x, w=t>>6, lane=t&63;
  int gm = blockIdx.y*128, gn = blockIdx.x*128;
  int wm = (w>>1)*64, wn = (w&1)*64;
  int lr = lane&15, lk = (lane>>4)*8;
  v4f acc[4][4];
  #pragma unroll
  for (int i=0;i<4;i++)
    #pragma unroll
    for (int j=0;j<4;j++){ v4f z = {0.f,0.f,0.f,0.f}; acc[i][j]=z; }
  for (int kk=0; kk<1024; kk+=32){
    __syncthreads();
    #pragma unroll
    for (int pass=0;pass<4;pass++){
      int slot=t+pass*256, row=slot>>3, c4=(slot&7)*4;
      float4 av = *(const float4*)&A[(size_t)(gm+row)*1024 + kk + c4];
      float4 bv = *(const float4*)&Bw[(size_t)(gn+row)*1024 + kk + c4];
      v4s at, bt;
      at[0]=(short)fbf(av.x); at[1]=(short)fbf(av.y); at[2]=(short)fbf(av.z); at[3]=(short)fbf(av.w);
      bt[0]=(short)fbf(bv.x); bt[1]=(short)fbf(bv.y); bt[2]=(short)fbf(bv.z); bt[3]=(short)fbf(bv.w);
      *(v4s*)&a_lds[row*40+c4] = at;
      *(v4s*)&b_lds[row*40+c4] = bt;
    }
    __syncthreads();
    v8s af[4], bfr[4];
    #pragma unroll
    for (int i=0;i<4;i++) af[i] = *(const v8s*)&a_lds[(wm+i*16+lr)*40+lk];
    #pragma unroll
    for (int j=0;j<4;j++) bfr[j] = *(const v8s*)&b_lds[(wn+j*16+lr)*40+lk];
    #pragma unroll
    for (int i=0;i<4;i++)
      #pragma unroll
      for (int j=0;j<4;j++)
        acc[i][j] = __builtin_amdgcn_mfma_f32_16x16x32_bf16(af[i], bfr[j], acc[i][j], 0,0,0);
  }
  int quad = lane>>4;
  #pragma unroll
  for (int j=0;j<4;j++){
    int gc = gn + wn + j*16 + lr;
    float bval = bias ? bias[gc] : 0.f;
    float gval = gate ? tanh_f(gate[gc]) : 1.f;
    #pragma unroll
    for (int i=0;i<4;i++){
      #pragma unroll
      for (int r=0;r<4;r++){
        int grow = gm + wm + i*16 + quad*4 + r;
        float v = (acc[i][j][r] + bval)*gval;
        if (res) v += res[(size_t)grow*1024 + gc];
        out[(size_t)grow*1024 + gc] = v;
      }
    }
  }
}

// ---------------- MFMA flash attention, block = (b,h,q-tile of 64) ----------------
__global__ __launch_bounds__(256) void attn_kernel(
    const float* __restrict__ Q, const float* __restrict__ K,
    const float* __restrict__ V, float* __restrict__ O)
{
  __shared__ __attribute__((aligned(16))) unsigned short q_l[64*68];
  __shared__ __attribute__((aligned(16))) unsigned short k_l[64*68];
  __shared__ __attribute__((aligned(16))) unsigned short vt_l[64*68]; // V^T [d][j]
  __shared__ __attribute__((aligned(16))) unsigned short p_l[64*68];
  int t=threadIdx.x, w=t>>6, lane=t&63, q=lane>>4, l16=lane&15;
  int qt = blockIdx.x & 15, bh = blockIdx.x >> 4;
  int b = bh >> 4, h = bh & 15;
  const size_t base = ((size_t)b*1024)*1024 + (size_t)h*64;
  #pragma unroll
  for (int pass=0;pass<4;pass++){
    int slot=t+pass*256, row=slot>>4, c4=(slot&15)*4;
    float4 v=*(const float4*)&Q[base + (size_t)(qt*64+row)*1024 + c4];
    v4s p; p[0]=(short)fbf(v.x); p[1]=(short)fbf(v.y); p[2]=(short)fbf(v.z); p[3]=(short)fbf(v.w);
    *(v4s*)&q_l[row*68+c4]=p;
  }
  float mi[4], li[4];
  v4f o[4];
  #pragma unroll
  for (int r=0;r<4;r++){ mi[r]=-1e30f; li[r]=0.f; }
  #pragma unroll
  for (int dtn=0;dtn<4;dtn++){ v4f z={0.f,0.f,0.f,0.f}; o[dtn]=z; }
  for (int kt=0; kt<=qt; kt++){
    __syncthreads();
    #pragma unroll
    for (int pass=0;pass<4;pass++){
      int slot=t+pass*256, row=slot>>4, c4=(slot&15)*4;
      float4 kv=*(const float4*)&K[base + (size_t)(kt*64+row)*1024 + c4];
      v4s kp; kp[0]=(short)fbf(kv.x); kp[1]=(short)fbf(kv.y); kp[2]=(short)fbf(kv.z); kp[3]=(short)fbf(kv.w);
      *(v4s*)&k_l[row*68+c4]=kp;
      float4 vv=*(const float4*)&V[base + (size_t)(kt*64+row)*1024 + c4];
      vt_l[(c4+0)*68+row]=fbf(vv.x);
      vt_l[(c4+1)*68+row]=fbf(vv.y);
      vt_l[(c4+2)*68+row]=fbf(vv.z);
      vt_l[(c4+3)*68+row]=fbf(vv.w);
    }
    __syncthreads();
    // S = Q@K^T (wave rows w*16..+15)
    v4f s[4];
    #pragma unroll
    for (int nt=0;nt<4;nt++){ v4f z={0.f,0.f,0.f,0.f}; s[nt]=z; }
    #pragma unroll
    for (int k2=0;k2<2;k2++){
      v8s af = ld8(&q_l[(w*16+l16)*68 + k2*32+q*8]);
      #pragma unroll
      for (int nt=0;nt<4;nt++){
        v8s bf = ld8(&k_l[(nt*16+l16)*68 + k2*32+q*8]);
        s[nt] = __builtin_amdgcn_mfma_f32_16x16x32_bf16(af, bf, s[nt], 0,0,0);
      }
    }
    bool diag = (kt==qt);
    #pragma unroll
    for (int r=0;r<4;r++){
      int row_l = w*16+q*4+r;
      float mx=-1e30f;
      #pragma unroll
      for (int nt=0;nt<4;nt++){
        int col=nt*16+l16;
        float sv = s[nt][r]*0.125f;
        if (diag && col>row_l) sv=-1e30f;
        s[nt][r]=sv; mx=fmaxf(mx,sv);
      }
      #pragma unroll
      for (int off=1;off<16;off<<=1) mx=fmaxf(mx,__shfl_xor(mx,off,16));
      float mnew=fmaxf(mi[r],mx);
      float aexp=__expf(mi[r]-mnew);
      float ps=0.f;
      #pragma unroll
      for (int nt=0;nt<4;nt++){
        float p=__expf(s[nt][r]-mnew);
        s[nt][r]=p; ps+=p;
      }
      #pragma unroll
      for (int off=1;off<16;off<<=1) ps+=__shfl_xor(ps,off,16);
      li[r]=li[r]*aexp+ps; mi[r]=mnew;
      #pragma unroll
      for (int dtn=0;dtn<4;dtn++) o[dtn][r]*=aexp;
      #pragma unroll
      for (int nt=0;nt<4;nt++) p_l[row_l*68 + nt*16+l16]=fbf(s[nt][r]);
    }
    __syncthreads();
    // O += P@V
    #pragma unroll
    for (int k2=0;k2<2;k2++){
      v8s af = ld8(&p_l[(w*16+l16)*68 + k2*32+q*8]);
      #pragma unroll
      for (int dtn=0;dtn<4;dtn++){
        v8s bf = ld8(&vt_l[(dtn*16+l16)*68 + k2*32+q*8]);
        o[dtn] = __builtin_amdgcn_mfma_f32_16x16x32_bf16(af, bf, o[dtn], 0,0,0);
      }
    }
  }
  #pragma unroll
  for (int dtn=0;dtn<4;dtn++)
    #pragma unroll
    for (int r=0;r<4;r++)
      O[base + (size_t)(qt*64+w*16+q*4+r)*1024 + dtn*16+l16] = o[dtn][r]/li[r];
}

// ------- XQ/XK normalize + XV fuse; write TTT layout [B,H,S,HD]. wave = (b,s,h) -------
__global__ __launch_bounds__(256) void xqkv_kernel(
    const float* __restrict__ XQ, const float* __restrict__ XK,
    const float* __restrict__ XV, const float* __restrict__ nw,
    const float* __restrict__ nb,
    float* __restrict__ xqt, float* __restrict__ xkt, float* __restrict__ xvt)
{
  int gw = (int)((blockIdx.x*256 + threadIdx.x)>>6);
  int lane = threadIdx.x & 63;
  int h = gw & 15, s = (gw>>4)&1023, b = gw>>14;
  size_t src = ((size_t)(b*1024+s))*1024 + h*64 + lane;
  float xq = XQ[src], xk = XK[src], xv = XV[src];
  float nq = sqrtf(wsum(xq*xq));
  float nk = sqrtf(wsum(xk*xk));
  float xqn = xq / fmaxf(nq, 1e-12f);
  float xkn = xk / fmaxf(nk, 1e-12f);
  float mu = wsum(xv)*(1.f/64.f);
  float xm = xv-mu;
  float var = wsum(xm*xm)*(1.f/64.f);
  float xvh = xm*rsqrtf(var+1e-6f);
  float xvn = nw[h*64+lane]*xvh + nb[h*64+lane] + xkn;
  size_t dst = ((size_t)(b*16+h)*1024 + s)*64 + lane;
  xqt[dst]=xqn; xkt[dst]=xkn; xvt[dst]=xvn;
}

// ------- eta[b,h,s] = sigmoid(x[b,s,:]·lr_w[h,:] + lr_b[h]) / 64. wave = (b,s) -------
__global__ __launch_bounds__(256) void eta_kernel(
    const float* __restrict__ Xb, const float* __restrict__ lrw,
    const float* __restrict__ lrb, float* __restrict__ eta)
{
  int gw = (int)((blockIdx.x*256 + threadIdx.x)>>6);
  int lane = threadIdx.x & 63;
  int s = gw & 1023, b = gw >> 10;
  const float* xrow = Xb + ((size_t)(b*1024+s))*1024;
  float xr[16];
  #pragma unroll
  for (int i=0;i<16;i++) xr[i] = xrow[i*64+lane];
  #pragma unroll 1
  for (int h=0;h<16;h++){
    const float* wr = lrw + h*1024;
    float acc=0.f;
    #pragma unroll
    for (int i=0;i<16;i++) acc += xr[i]*wr[i*64+lane];
    acc = wsum(acc);
    if (lane==h){
      float vv = acc + lrb[h];
      float sg = 1.f/(1.f+__expf(-vv));
      eta[((size_t)(b*16+h))*1024 + s] = sg*(1.f/64.f);
    }
  }
}

// ---------------- TTT scan (MFMA, LDS-resident, transposed operand layouts) ----------------
// One 512-thread block per (b,h). W1/W2 f32 masters in registers (C-frag layouts).
// All MFMA B-frags are contiguous ld8: W1t [n][k], W2T [d][k], GZ1t [n][j], GZ2t [d][j].
__global__ __launch_bounds__(512) void scan_kernel(
    const float* __restrict__ xqt, const float* __restrict__ xkt,
    const float* __restrict__ xvt, const float* __restrict__ eta,
    const float* __restrict__ W1in, const float* __restrict__ b1in,
    const float* __restrict__ W2in, const float* __restrict__ b2in,
    const float* __restrict__ nw, const float* __restrict__ nb,
    float* __restrict__ tout)
{
  __shared__ __attribute__((aligned(16))) unsigned short W1t[256*68];  // W1^T [n][k]
  __shared__ __attribute__((aligned(16))) unsigned short W2T[64*260];  // W2^T [d][k]
  __shared__ __attribute__((aligned(16))) unsigned short X2s[64*260];  // X2 [m][n]
  __shared__ __attribute__((aligned(16))) unsigned short GXu[256*68];  // GZ1t [n][j] / X2b [m][n](260)
  __shared__ __attribute__((aligned(16))) unsigned short GZ2t[64*68];  // gZ2^T [d][j]
  __shared__ __attribute__((aligned(16))) unsigned short AMs[64*68];   // -tril(eta*(A+1)) [m][j]
  __shared__ float ln_scr[64*8];
  __shared__ float eta_s[64], b1_s[256], b2_s[64], nw_s[64], nb_s[64];

  const int t=threadIdx.x, w=t>>6, lane=t&63, q=lane>>4, l16=lane&15;
  const int bh=blockIdx.x, b=bh>>4, h=bh&15;
  const int mt=w>>1, nh=(w&1)*8, nh4=(w&1)*2;
  const float* xq_g = xqt + (size_t)bh*65536;
  const float* xk_g = xkt + (size_t)bh*65536;
  const float* xv_g = xvt + (size_t)bh*65536;
  const float* eta_g = eta + (size_t)bh*1024;

  float w1r[8][4];
  #pragma unroll
  for (int nt=0;nt<8;nt++){
    int col=(nh+nt)*16+l16;
    #pragma unroll
    for (int r=0;r<4;r++) w1r[nt][r] = W1in[h*16384 + (mt*16+q*4+r)*256 + col];
  }
  float w2r[2][4][4];
  #pragma unroll
  for (int mi=0;mi<2;mi++)
    #pragma unroll
    for (int nt=0;nt<4;nt++){
      int col=nt*16+l16;
      #pragma unroll
      for (int r=0;r<4;r++) w2r[mi][nt][r] = W2in[h*16384 + ((w*2+mi)*16+q*4+r)*64 + col];
    }
  if (t<256) b1_s[t]=b1in[h*256+t];
  if (t<64){ b2_s[t]=b2in[h*64+t]; nw_s[t]=nw[h*64+t]; nb_s[t]=nb[h*64+t]; }

  for (int n=0;n<16;n++){
    __syncthreads();
    // ---- stage bf16 W copies (transposed) ----
    #pragma unroll
    for (int nt=0;nt<8;nt++){
      int col=(nh+nt)*16+l16;
      #pragma unroll
      for (int pr=0;pr<2;pr++){
        unsigned lo=fbf(w1r[nt][pr*2]), hi=fbf(w1r[nt][pr*2+1]);
        *(unsigned*)&W1t[col*68 + mt*16+q*4 + pr*2] = lo | (hi<<16);
      }
    }
    #pragma unroll
    for (int mi=0;mi<2;mi++)
      #pragma unroll
      for (int nt=0;nt<4;nt++){
        int col=nt*16+l16;
        #pragma unroll
        for (int pr=0;pr<2;pr++){
          unsigned lo=fbf(w2r[mi][nt][pr*2]), hi=fbf(w2r[mi][nt][pr*2+1]);
          *(unsigned*)&W2T[col*260 + (w*2+mi)*16+q*4 + pr*2] = lo | (hi<<16);
        }
      }
    if (t<64) eta_s[t]=eta_g[n*64+t];
    __syncthreads();

    // ---- P1: Z1 = xk@W1 + b1 (stays in a1); X2 -> X2s. P4: AMs. ----
    v4f a1[8];
    #pragma unroll
    for (int i=0;i<8;i++){ v4f z={0.f,0.f,0.f,0.f}; a1[i]=z; }
    v8s xqf[2];
    #pragma unroll
    for (int kt=0;kt<2;kt++){
      v8s af = cv8(xk_g + n*4096 + (mt*16+l16)*64 + kt*32+q*8);
      #pragma unroll
      for (int nt=0;nt<8;nt++){
        v8s bf = ld8(&W1t[((nh+nt)*16+l16)*68 + kt*32+q*8]);
        a1[nt] = __builtin_amdgcn_mfma_f32_16x16x32_bf16(af, bf, a1[nt], 0,0,0);
      }
    }
    #pragma unroll
    for (int nt=0;nt<8;nt++){
      int col=(nh+nt)*16+l16; float bb=b1_s[col];
      #pragma unroll
      for (int r=0;r<4;r++){
        float z=clampv(a1[nt][r]+bb); a1[nt][r]=z;
        X2s[(mt*16+q*4+r)*260+col]=fbf(clampv(gelu_f(z)));
      }
    }
    {
      v4f a4[2];
      #pragma unroll
      for (int i=0;i<2;i++){ v4f z={0.f,0.f,0.f,0.f}; a4[i]=z; }
      #pragma unroll
      for (int kt=0;kt<2;kt++){
        xqf[kt] = cv8(xq_g + n*4096 + (mt*16+l16)*64 + kt*32+q*8);
        #pragma unroll
        for (int nt=0;nt<2;nt++){
          v8s bf = cv8(xk_g + n*4096 + ((nh4+nt)*16+l16)*64 + kt*32+q*8);
          a4[nt] = __builtin_amdgcn_mfma_f32_16x16x32_bf16(xqf[kt], bf, a4[nt], 0,0,0);
        }
      }
      #pragma unroll
      for (int nt=0;nt<2;nt++){
        int col=(nh4+nt)*16+l16;
        float ec=eta_s[col];
        #pragma unroll
        for (int r=0;r<4;r++){
          int row=mt*16+q*4+r;
          AMs[row*68+col] = (col<=row) ? fbf(-ec*(a4[nt][r]+1.f)) : (unsigned short)0;
        }
      }
    }
    __syncthreads();

    // ---- P2: Z2 = X2@W2 + b2 ; LN2 -> GZ2t ----
    {
      v4f a2[2];
      #pragma unroll
      for (int i=0;i<2;i++){ v4f z={0.f,0.f,0.f,0.f}; a2[i]=z; }
      #pragma unroll
      for (int kt=0;kt<8;kt++){
        v8s af = ld8(&X2s[(mt*16+l16)*260 + kt*32+q*8]);
        #pragma unroll
        for (int nt=0;nt<2;nt++){
          v8s bf = ld8(&W2T[((nh4+nt)*16+l16)*260 + kt*32+q*8]);
          a2[nt] = __builtin_amdgcn_mfma_f32_16x16x32_bf16(af, bf, a2[nt], 0,0,0);
        }
      }
      float z2[2][4];
      #pragma unroll
      for (int nt=0;nt<2;nt++){
        float bb=b2_s[(nh4+nt)*16+l16];
        #pragma unroll
        for (int r=0;r<4;r++) z2[nt][r]=clampv(a2[nt][r]+bb);
      }
      #pragma unroll
      for (int r=0;r<4;r++){
        float s1v=z2[0][r]+z2[1][r];
        float s2v=z2[0][r]*z2[0][r]+z2[1][r]*z2[1][r];
        #pragma unroll
        for (int off=1;off<16;off<<=1){ s1v+=__shfl_xor(s1v,off,16); s2v+=__shfl_xor(s2v,off,16); }
        if (l16==0){ int row=mt*16+q*4+r; ln_scr[row*8+(w&1)]=s1v; ln_scr[row*8+2+(w&1)]=s2v; }
      }
      __syncthreads();
      float muv[4], istd[4];
      #pragma unroll
      for (int r=0;r<4;r++){
        int row=mt*16+q*4+r;
        float S1=ln_scr[row*8+0]+ln_scr[row*8+1];
        float S2=ln_scr[row*8+2]+ln_scr[row*8+3];
        float mu=S1*(1.f/64.f);
        float var=fmaxf(S2*(1.f/64.f)-mu*mu, 0.f);
        muv[r]=mu; istd[r]=rsqrtf(var+1e-6f);
      }
      float xh[2][4], gh[2][4];
      #pragma unroll
      for (int nt=0;nt<2;nt++){
        int col=(nh4+nt)*16+l16;
        float gw_=nw_s[col], gb_=nb_s[col];
        #pragma unroll
        for (int r=0;r<4;r++){
          int row=mt*16+q*4+r;
          float x_=(z2[nt][r]-muv[r])*istd[r];
          float tgt = xv_g[n*4096+row*64+col] - xk_g[n*4096+row*64+col];
          xh[nt][r]=x_;
          gh[nt][r]=(gw_*x_+gb_-tgt)*gw_;
        }
      }
      #pragma unroll
      for (int r=0;r<4;r++){
        float t1=gh[0][r]+gh[1][r];
        float t2=gh[0][r]*xh[0][r]+gh[1][r]*xh[1][r];
        #pragma unroll
        for (int off=1;off<16;off<<=1){ t1+=__shfl_xor(t1,off,16); t2+=__shfl_xor(t2,off,16); }
        if (l16==0){ int row=mt*16+q*4+r; ln_scr[row*8+4+(w&1)]=t1; ln_scr[row*8+6+(w&1)]=t2; }
      }
      __syncthreads();
      #pragma unroll
      for (int nt=0;nt<2;nt++){
        int col=(nh4+nt)*16+l16;
        #pragma unroll
        for (int r=0;r<4;r++){
          int row=mt*16+q*4+r;
          float G1s=ln_scr[row*8+4]+ln_scr[row*8+5];
          float G2s=ln_scr[row*8+6]+ln_scr[row*8+7];
          float gz=(64.f*gh[nt][r]-G1s-xh[nt][r]*G2s)*istd[r]*(1.f/64.f);
          GZ2t[col*68+row]=fbf(clampv(gz));
        }
      }
    }
    __syncthreads();

    // ---- P3: gZ1 = (gZ2@W2^T) * gelu'(Z1) -> GZ1t [n][j] ----
    {
      v4f a3[8];
      #pragma unroll
      for (int i=0;i<8;i++){ v4f z={0.f,0.f,0.f,0.f}; a3[i]=z; }
      #pragma unroll
      for (int kt=0;kt<2;kt++){
        v8s af;
        #pragma unroll
        for (int j=0;j<8;j++) af[j]=(short)GZ2t[(kt*32+q*8+j)*68 + mt*16+l16];
        #pragma unroll
        for (int nt=0;nt<8;nt++){
          int nb0=(nh+nt)*16+l16;
          v8s bf;
          #pragma unroll
          for (int j=0;j<8;j++) bf[j]=(short)W2T[(kt*32+q*8+j)*260 + nb0];
          a3[nt] = __builtin_amdgcn_mfma_f32_16x16x32_bf16(af, bf, a3[nt], 0,0,0);
        }
      }
      #pragma unroll
      for (int nt=0;nt<8;nt++){
        int col=(nh+nt)*16+l16;
        #pragma unroll
        for (int pr=0;pr<2;pr++){
          float g0=clampv(a3[nt][pr*2+0]*gelu_bwd_f(a1[nt][pr*2+0]));
          float g1=clampv(a3[nt][pr*2+1]*gelu_bwd_f(a1[nt][pr*2+1]));
          unsigned lo=fbf(g0), hi=fbf(g1);
          *(unsigned*)&GXu[col*68 + mt*16+q*4 + pr*2] = lo | (hi<<16);
        }
      }
    }
    __syncthreads();

    // ---- P5: Z1b = xq@W1 + AMs@gZ1 + b1 ; H1: W1regs -= (eta xk)^T @ gZ1 ; b1 colsum ----
    v4f a5[8];
    float bbold[8];
    float bacc=0.f;
    {
      if (t<256){
        #pragma unroll
        for (int j4=0;j4<16;j4++){
          v4s v=*(const v4s*)&GXu[t*68+j4*4];
          bacc += eta_s[j4*4+0]*bfu((unsigned short)v[0]) + eta_s[j4*4+1]*bfu((unsigned short)v[1])
                + eta_s[j4*4+2]*bfu((unsigned short)v[2]) + eta_s[j4*4+3]*bfu((unsigned short)v[3]);
        }
      }
      v4f a6[8];
      #pragma unroll
      for (int i=0;i<8;i++){ v4f z={0.f,0.f,0.f,0.f}; a5[i]=z; a6[i]=z; }
      #pragma unroll
      for (int nt=0;nt<8;nt++) bbold[nt]=b1_s[(nh+nt)*16+l16];
      #pragma unroll
      for (int kt=0;kt<2;kt++){
        #pragma unroll
        for (int nt=0;nt<8;nt++){
          v8s bf = ld8(&W1t[((nh+nt)*16+l16)*68 + kt*32+q*8]);
          a5[nt] = __builtin_amdgcn_mfma_f32_16x16x32_bf16(xqf[kt], bf, a5[nt], 0,0,0);
        }
      }
      #pragma unroll
      for (int kt=0;kt<2;kt++){
        v8s afA = ld8(&AMs[(mt*16+l16)*68 + kt*32+q*8]);
        v8s afE;
        #pragma unroll
        for (int j=0;j<8;j++){
          int jj=kt*32+q*8+j;
          afE[j]=(short)fbf(eta_s[jj]*xk_g[n*4096 + jj*64 + mt*16+l16]);
        }
        #pragma unroll
        for (int nt=0;nt<8;nt++){
          v8s bf = ld8(&GXu[((nh+nt)*16+l16)*68 + kt*32+q*8]);
          a5[nt] = __builtin_amdgcn_mfma_f32_16x16x32_bf16(afA, bf, a5[nt], 0,0,0);
          a6[nt] = __builtin_amdgcn_mfma_f32_16x16x32_bf16(afE, bf, a6[nt], 0,0,0);
        }
      }
      #pragma unroll
      for (int nt=0;nt<8;nt++)
        #pragma unroll
        for (int r=0;r<4;r++) w1r[nt][r] -= a6[nt][r];
    }
    __syncthreads();
    // ---- X2b = gelu(Z1b) -> GXu row-major [m][n](260) ; apply b1 update ----
    #pragma unroll
    for (int nt=0;nt<8;nt++){
      int col=(nh+nt)*16+l16;
      #pragma unroll
      for (int r=0;r<4;r++){
        float z=clampv(a5[nt][r]+bbold[nt]);
        GXu[(mt*16+q*4+r)*260+col]=fbf(clampv(gelu_f(z)));
      }
    }
    if (t<256) b1_s[t] -= bacc;
    __syncthreads();

    // ---- P6: AMs = -tril(eta_j*(X2b@X2^T + 1)) ; b2 colsum ----
    float bacc2=0.f;
    {
      if (t<64){
        #pragma unroll
        for (int j4=0;j4<16;j4++){
          v4s v=*(const v4s*)&GZ2t[t*68+j4*4];
          bacc2 += eta_s[j4*4+0]*bfu((unsigned short)v[0]) + eta_s[j4*4+1]*bfu((unsigned short)v[1])
                 + eta_s[j4*4+2]*bfu((unsigned short)v[2]) + eta_s[j4*4+3]*bfu((unsigned short)v[3]);
        }
      }
      v4f a7[2];
      #pragma unroll
      for (int i=0;i<2;i++){ v4f z={0.f,0.f,0.f,0.f}; a7[i]=z; }
      #pragma unroll
      for (int kt=0;kt<8;kt++){
        v8s af = ld8(&GXu[(mt*16+l16)*260 + kt*32+q*8]);   // X2b
        #pragma unroll
        for (int nt=0;nt<2;nt++){
          v8s bf = ld8(&X2s[((nh4+nt)*16+l16)*260 + kt*32+q*8]);
          a7[nt] = __builtin_amdgcn_mfma_f32_16x16x32_bf16(af, bf, a7[nt], 0,0,0);
        }
      }
      __syncthreads();  // AMs fully consumed at P5
      #pragma unroll
      for (int nt=0;nt<2;nt++){
        int col=(nh4+nt)*16+l16;
        float ec=eta_s[col];
        #pragma unroll
        for (int r=0;r<4;r++){
          int row=mt*16+q*4+r;
          AMs[row*68+col] = (col<=row) ? fbf(-ec*(a7[nt][r]+1.f)) : (unsigned short)0;
        }
      }
    }
    __syncthreads();

    // ---- P7: Z2b = X2b@W2 + AMs@gZ2 + b2 ; LN7 -> tout ; H2 ----
    {
      v4f a8[2];
      #pragma unroll
      for (int i=0;i<2;i++){ v4f z={0.f,0.f,0.f,0.f}; a8[i]=z; }
      float b2old[2];
      #pragma unroll
      for (int nt=0;nt<2;nt++) b2old[nt]=b2_s[(nh4+nt)*16+l16];
      #pragma unroll
      for (int kt=0;kt<8;kt++){
        v8s af = ld8(&GXu[(mt*16+l16)*260 + kt*32+q*8]);   // X2b
        #pragma unroll
        for (int nt=0;nt<2;nt++){
          v8s bf = ld8(&W2T[((nh4+nt)*16+l16)*260 + kt*32+q*8]);
          a8[nt] = __builtin_amdgcn_mfma_f32_16x16x32_bf16(af, bf, a8[nt], 0,0,0);
        }
      }
      #pragma unroll
      for (int kt=0;kt<2;kt++){
        v8s af = ld8(&AMs[(mt*16+l16)*68 + kt*32+q*8]);
        #pragma unroll
        for (int nt=0;nt<2;nt++){
          v8s bf = ld8(&GZ2t[((nh4+nt)*16+l16)*68 + kt*32+q*8]);
          a8[nt] = __builtin_amdgcn_mfma_f32_16x16x32_bf16(af, bf, a8[nt], 0,0,0);
        }
      }
      float z2b[2][4];
      #pragma unroll
      for (int nt=0;nt<2;nt++)
        #pragma unroll
        for (int r=0;r<4;r++) z2b[nt][r]=clampv(a8[nt][r]+b2old[nt]);
      #pragma unroll
      for (int r=0;r<4;r++){
        float s1v=z2b[0][r]+z2b[1][r];
        float s2v=z2b[0][r]*z2b[0][r]+z2b[1][r]*z2b[1][r];
        #pragma unroll
        for (int off=1;off<16;off<<=1){ s1v+=__shfl_xor(s1v,off,16); s2v+=__shfl_xor(s2v,off,16); }
        if (l16==0){ int row=mt*16+q*4+r; ln_scr[row*8+(w&1)]=s1v; ln_scr[row*8+2+(w&1)]=s2v; }
      }
      __syncthreads();
      #pragma unroll
      for (int r=0;r<4;r++){
        int row=mt*16+q*4+r;
        float S1=ln_scr[row*8+0]+ln_scr[row*8+1];
        float S2=ln_scr[row*8+2]+ln_scr[row*8+3];
        float mu=S1*(1.f/64.f);
        float var=fmaxf(S2*(1.f/64.f)-mu*mu, 0.f);
        float istd=rsqrtf(var+1e-6f);
        #pragma unroll
        for (int nt=0;nt<2;nt++){
          int col=(nh4+nt)*16+l16;
          float x_=(z2b[nt][r]-mu)*istd;
          float outv = xq_g[n*4096+row*64+col] + x_*nw_s[col] + nb_s[col];
          tout[((size_t)(b*1024 + n*64 + row))*1024 + h*64 + col] = outv;
        }
      }
      // H2: W2regs -= (eta X2)^T @ gZ2
      v4f a9[2][4];
      #pragma unroll
      for (int mi=0;mi<2;mi++)
        #pragma unroll
        for (int c=0;c<4;c++){ v4f z={0.f,0.f,0.f,0.f}; a9[mi][c]=z; }
      #pragma unroll
      for (int kt=0;kt<2;kt++){
        v8s bfs[4];
        #pragma unroll
        for (int nt=0;nt<4;nt++) bfs[nt] = ld8(&GZ2t[(nt*16+l16)*68 + kt*32+q*8]);
        #pragma unroll
        for (int mi=0;mi<2;mi++){
          v8s af;
          #pragma unroll
          for (int j=0;j<8;j++){
            int jj=kt*32+q*8+j;
            af[j]=(short)fbf(eta_s[jj]*bfu(X2s[jj*260 + (w*2+mi)*16+l16]));
          }
          #pragma unroll
          for (int nt=0;nt<4;nt++)
            a9[mi][nt] = __builtin_amdgcn_mfma_f32_16x16x32_bf16(af, bfs[nt], a9[mi][nt], 0,0,0);
        }
      }
      #pragma unroll
      for (int mi=0;mi<2;mi++)
        #pragma unroll
        for (int nt=0;nt<4;nt++)
          #pragma unroll
          for (int r=0;r<4;r++) w2r[mi][nt][r] -= a9[mi][nt][r];
      if (t<64) b2_s[t] -= bacc2;
    }
  }
}

extern "C" void kernel_launch(void* const* d_in, const int* in_sizes, int n_in,
                              void* d_out, int out_size, void* d_ws, size_t ws_size,
                              hipStream_t stream)
{
  const float* x_in   = (const float*)d_in[0];
  const float* ln1w   = (const float*)d_in[1];
  const float* ln1b   = (const float*)d_in[2];
  const float* awq    = (const float*)d_in[3];
  const float* awk    = (const float*)d_in[4];
  const float* awv    = (const float*)d_in[5];
  const float* awo    = (const float*)d_in[6];
  const float* wqw    = (const float*)d_in[7];
  const float* wqb    = (const float*)d_in[8];
  const float* wkw    = (const float*)d_in[9];
  const float* wkb    = (const float*)d_in[10];
  const float* wvw    = (const float*)d_in[11];
  const float* wvb    = (const float*)d_in[12];
  const float* wow    = (const float*)d_in[13];
  const float* wob    = (const float*)d_in[14];
  const float* W1in   = (const float*)d_in[15];
  const float* b1in   = (const float*)d_in[16];
  const float* W2in   = (const float*)d_in[17];
  const float* b2in   = (const float*)d_in[18];
  const float* tnw    = (const float*)d_in[19];
  const float* tnb    = (const float*)d_in[20];
  const float* lrw    = (const float*)d_in[21];
  const float* lrb    = (const float*)d_in[22];
  const float* pnw    = (const float*)d_in[23];
  const float* pnb    = (const float*)d_in[24];
  const float* galpha = (const float*)d_in[25];
  float* outp = (float*)d_out;
  char* ws = (char*)d_ws;
  const size_t MB = (size_t)1<<20;
  float* bq  = (float*)(ws + 0*MB);
  float* bk  = (float*)(ws + 16*MB);
  float* bv  = (float*)(ws + 32*MB);
  float* bhh = (float*)(ws + 48*MB);
  float* bo  = (float*)(ws + 64*MB);
  float* bxb = (float*)(ws + 80*MB);
  float* xqt = (float*)(ws + 96*MB);
  float* xkt = (float*)(ws + 112*MB);
  float* xvt = (float*)(ws + 128*MB);
  float* eta  = (float*)(ws + 144*MB);
  float* tout = bo;
  float* bhh2 = bhh;

  dim3 gg(8,32);
  ln_kernel<<<4096,256,0,stream>>>(x_in, ln1w, ln1b, bhh);
  gemm_kernel<<<gg,256,0,stream>>>(bhh, awq, nullptr, nullptr, nullptr, bq);
  gemm_kernel<<<gg,256,0,stream>>>(bhh, awk, nullptr, nullptr, nullptr, bk);
  gemm_kernel<<<gg,256,0,stream>>>(bhh, awv, nullptr, nullptr, nullptr, bv);
  attn_kernel<<<1024,256,0,stream>>>(bq,bk,bv,bo);
  gemm_kernel<<<gg,256,0,stream>>>(bo, awo, nullptr, x_in, nullptr, bxb);
  gemm_kernel<<<gg,256,0,stream>>>(bxb, wqw, wqb, nullptr, nullptr, bq);
  gemm_kernel<<<gg,256,0,stream>>>(bxb, wkw, wkb, nullptr, nullptr, bk);
  gemm_kernel<<<gg,256,0,stream>>>(bxb, wvw, wvb, nullptr, nullptr, bv);
  xqkv_kernel<<<16384,256,0,stream>>>(bq,bk,bv,tnw,tnb,xqt,xkt,xvt);
  eta_kernel<<<1024,256,0,stream>>>(bxb, lrw, lrb, eta);
  scan_kernel<<<64,512,0,stream>>>(xqt,xkt,xvt,eta,W1in,b1in,W2in,b2in,tnw,tnb,tout);
  ln_kernel<<<4096,256,0,stream>>>(tout, pnw, pnb, bhh2);
  gemm_kernel<<<gg,256,0,stream>>>(bhh2, wow, wob, bxb, galpha, outp);
}